// Round 5
// baseline (1112.818 us; speedup 1.0000x reference)
//
#include <hip/hip_runtime.h>
#include <stdint.h>

#pragma clang fp contract(off)

#define BATCH   16
#define NPTS    4096
#define NPOINT  1024
#define NSAMPLE 32
#define NPOS    (BATCH*NPOINT*NSAMPLE)   // 524288
#define EPSV    1e-5f

typedef unsigned short ushort_t;
typedef unsigned int uint_t;
typedef unsigned long long u64;
typedef __attribute__((ext_vector_type(8))) short bf16x8;
typedef __attribute__((ext_vector_type(4))) float f32x4;
typedef __attribute__((ext_vector_type(2))) float f32x2;

__device__ inline ushort_t f2bf(float f) {
    uint_t u = __float_as_uint(f);
    u += 0x7fffu + ((u >> 16) & 1u);   // RNE (no NaNs in this workload)
    return (ushort_t)(u >> 16);
}
__device__ inline void unpack8(uint4 u, float* f) {
    f[0] = __uint_as_float(u.x << 16); f[1] = __uint_as_float(u.x & 0xffff0000u);
    f[2] = __uint_as_float(u.y << 16); f[3] = __uint_as_float(u.y & 0xffff0000u);
    f[4] = __uint_as_float(u.z << 16); f[5] = __uint_as_float(u.z & 0xffff0000u);
    f[6] = __uint_as_float(u.w << 16); f[7] = __uint_as_float(u.w & 0xffff0000u);
}

// ---------------------------------------------------------------- zero stats
__global__ void zero_kernel(float* __restrict__ p, int n) {
    int i = blockIdx.x * blockDim.x + threadIdx.x;
    if (i < n) p[i] = 0.f;
}

// ---------------------------------------------------------------- FPS
// One block per batch, 256 threads. 16 pts/thread as 8 float2 pairs ->
// v_pk_add/mul_f32 halve the issue cost of the distance update. Packed-u64
// tree reduce -> DPP wave reduce -> parity-LDS cross-wave reduce, 1 barrier.
// Exact fp32 op order (contract off) to match np reference argmax.
#define DPP_MAX_STAGE(CTRL) do {                                              \
    uint_t _lo2 = __builtin_amdgcn_update_dpp(lo, lo, CTRL, 0xf, 0xf, false); \
    uint_t _hi2 = __builtin_amdgcn_update_dpp(hi, hi, CTRL, 0xf, 0xf, false); \
    u64 _o = ((u64)_hi2 << 32) | _lo2;                                        \
    u64 _v = ((u64)hi << 32) | lo;                                            \
    bool _g = _o > _v;                                                        \
    lo = _g ? _lo2 : lo; hi = _g ? _hi2 : hi;                                 \
} while (0)

__global__ __launch_bounds__(256) void fps_kernel(const float* __restrict__ xyz,
                                                  float* __restrict__ new_xyz) {
    __shared__ float4 lxyz[NPTS];     // 64 KiB
    __shared__ u64 wbest[2][4];
    __shared__ int fpsidx[NPOINT];
    const int b = blockIdx.x;
    const int tid = threadIdx.x;
    const float* base = xyz + (size_t)b * NPTS * 3;
    for (int n = tid; n < NPTS; n += 256) {
        lxyz[n] = make_float4(base[3 * n], base[3 * n + 1], base[3 * n + 2], 0.f);
    }
    __syncthreads();

    f32x2 px[8], py[8], pz[8], dist[8];
    uint_t lowc[16];   // ~idx, iteration-invariant (smaller idx wins ties)
#pragma unroll
    for (int j = 0; j < 8; j++) {
        float4 v0 = lxyz[tid + (2 * j) * 256];
        float4 v1 = lxyz[tid + (2 * j + 1) * 256];
        px[j] = (f32x2){v0.x, v1.x};
        py[j] = (f32x2){v0.y, v1.y};
        pz[j] = (f32x2){v0.z, v1.z};
        dist[j] = (f32x2){1e10f, 1e10f};
        lowc[2 * j] = ~(uint_t)(tid + (2 * j) * 256);
        lowc[2 * j + 1] = ~(uint_t)(tid + (2 * j + 1) * 256);
    }
    if (tid == 0) fpsidx[0] = 0;
    int cur = 0;
    const int lane = tid & 63, wid = tid >> 6;

    for (int it = 1; it < NPOINT; ++it) {
        float4 c = lxyz[cur];
        const f32x2 cx = (f32x2){c.x, c.x};
        const f32x2 cy = (f32x2){c.y, c.y};
        const f32x2 cz = (f32x2){c.z, c.z};
        u64 t[8];
#pragma unroll
        for (int j = 0; j < 8; j++) {
            f32x2 dx = px[j] - cx;
            f32x2 dy = py[j] - cy;
            f32x2 dz = pz[j] - cz;
            f32x2 d = (dx * dx + dy * dy) + dz * dz;   // contract OFF: mul,mul,add,mul,add
            f32x2 nd = __builtin_elementwise_min(dist[j], d);
            dist[j] = nd;
            u64 e0 = ((u64)__float_as_uint(nd.x) << 32) | lowc[2 * j];
            u64 e1 = ((u64)__float_as_uint(nd.y) << 32) | lowc[2 * j + 1];
            t[j] = e0 > e1 ? e0 : e1;
        }
#pragma unroll
        for (int j = 0; j < 4; j++) { u64 o = t[j + 4]; t[j] = t[j] > o ? t[j] : o; }
        t[0] = t[0] > t[1] ? t[0] : t[1];
        t[2] = t[2] > t[3] ? t[2] : t[3];
        u64 v = t[0] > t[2] ? t[0] : t[2];

        uint_t lo = (uint_t)v, hi = (uint_t)(v >> 32);
        DPP_MAX_STAGE(0x111);   // row_shr:1
        DPP_MAX_STAGE(0x112);   // row_shr:2
        DPP_MAX_STAGE(0x114);   // row_shr:4
        DPP_MAX_STAGE(0x118);   // row_shr:8
        DPP_MAX_STAGE(0x142);   // row_bcast:15
        DPP_MAX_STAGE(0x143);   // row_bcast:31
        uint_t mlo = __builtin_amdgcn_readlane(lo, 63);
        uint_t mhi = __builtin_amdgcn_readlane(hi, 63);

        const int par = it & 1;
        if (lane == 0) wbest[par][wid] = ((u64)mhi << 32) | mlo;
        __syncthreads();
        u64 b0 = wbest[par][0], b1 = wbest[par][1];
        u64 b2 = wbest[par][2], b3 = wbest[par][3];
        u64 m01 = b0 > b1 ? b0 : b1;
        u64 m23 = b2 > b3 ? b2 : b3;
        u64 bb = m01 > m23 ? m01 : m23;
        cur = (int)(~(uint_t)bb) & (NPTS - 1);
        if (tid == 0) fpsidx[it] = cur;
        // parity buffering: next write to this slot is 2 barriers away -> safe
    }
    __syncthreads();
    float* ob = new_xyz + (size_t)b * NPOINT * 3;
    for (int s = tid; s < NPOINT; s += 256) {
        float4 v = lxyz[fpsidx[s]];
        ob[3 * s + 0] = v.x; ob[3 * s + 1] = v.y; ob[3 * s + 2] = v.z;
    }
}

// ---------------------------------------------------------------- ball query
__global__ __launch_bounds__(256) void ballq_kernel(const float* __restrict__ xyz,
                                                    const float* __restrict__ new_xyz,
                                                    int* __restrict__ gidx) {
    const int gw = (int)((blockIdx.x * 256 + threadIdx.x) >> 6);
    const int lane = threadIdx.x & 63;
    const int b = gw / NPOINT, s = gw % NPOINT;
    const float* nb = new_xyz + ((size_t)b * NPOINT + s) * 3;
    const float cx = nb[0], cy = nb[1], cz = nb[2];
    const float* xb = xyz + (size_t)b * NPTS * 3;
    const float r2 = (float)(0.2 * 0.2);
    int cnt = 0;
    int first = -1;
    int* out = gidx + (size_t)gw * NSAMPLE;
    for (int j0 = 0; j0 < NPTS; j0 += 64) {
        int j = j0 + lane;
        float dx = __fsub_rn(xb[j * 3 + 0], cx);
        float dy = __fsub_rn(xb[j * 3 + 1], cy);
        float dz = __fsub_rn(xb[j * 3 + 2], cz);
        float d = __fadd_rn(__fadd_rn(__fmul_rn(dx, dx), __fmul_rn(dy, dy)),
                            __fmul_rn(dz, dz));
        bool pred = !(d > r2);
        u64 mask = __ballot(pred);
        if (first < 0 && mask != 0ull) first = j0 + (__ffsll((long long)mask) - 1);
        int before = __popcll(mask & ((1ull << lane) - 1ull));
        int slot = cnt + before;
        if (pred && slot < NSAMPLE) out[slot] = j;
        cnt += (int)__popcll(mask);
        if (cnt >= NSAMPLE) break;
    }
    if (cnt < NSAMPLE) {
        if (lane >= cnt && lane < NSAMPLE) out[lane] = first;
    }
}

// ---------------------------------------------------------------- conv1 (MFMA + fused stats)
// 128 positions/block, 4 waves x 32 pos (2 m-tiles). K split: points ch (32)
// as one MFMA slice, xyz-norm (3) in k=0..2 of a sparse second slice.
// Epilogue: bf16-round, store, and block-reduce sum/sumsq -> atomicAdd.
__global__ __launch_bounds__(256) void conv1_mfma(const float* __restrict__ xyz,
                                                  const float* __restrict__ points,
                                                  const float* __restrict__ new_xyz,
                                                  const int* __restrict__ gidx,
                                                  const float* __restrict__ W,
                                                  const float* __restrict__ bias,
                                                  ushort_t* __restrict__ Y,
                                                  float* __restrict__ sums,
                                                  float* __restrict__ sq) {
    const int lane = threadIdx.x & 63, wid = threadIdx.x >> 6;
    const int l15 = lane & 15, quad = lane >> 4;
    const int p0 = blockIdx.x * 128 + wid * 32;

    bf16x8 Bp[4], Bx[4];
#pragma unroll
    for (int nt = 0; nt < 4; nt++) {
        const float* wr = W + (size_t)(nt * 16 + l15) * 35;
#pragma unroll
        for (int q = 0; q < 8; q++) Bp[nt][q] = (short)f2bf(wr[3 + quad * 8 + q]);
#pragma unroll
        for (int q = 0; q < 8; q++)
            Bx[nt][q] = (quad == 0 && q < 3) ? (short)f2bf(wr[q]) : (short)0;
    }
    f32x4 acc[2][4];
#pragma unroll
    for (int mt = 0; mt < 2; mt++)
#pragma unroll
        for (int nt = 0; nt < 4; nt++) acc[mt][nt] = (f32x4){0.f, 0.f, 0.f, 0.f};

#pragma unroll
    for (int mt = 0; mt < 2; mt++) {
        const int p = p0 + mt * 16 + l15;
        const int b = p >> 15, s = (p & 32767) >> 5;
        const int j = gidx[p];
        const float* pr = points + ((size_t)(b * NPTS + j)) * 32 + quad * 8;
        bf16x8 Ap, Ax;
#pragma unroll
        for (int q = 0; q < 8; q++) Ap[q] = (short)f2bf(pr[q]);
#pragma unroll
        for (int q = 0; q < 8; q++) Ax[q] = 0;
        const float* xp = xyz + ((size_t)(b * NPTS + j)) * 3;
        const float* nz = new_xyz + ((size_t)(b * NPOINT + s)) * 3;
        if (quad == 0) {
            Ax[0] = (short)f2bf(xp[0] - nz[0]);
            Ax[1] = (short)f2bf(xp[1] - nz[1]);
            Ax[2] = (short)f2bf(xp[2] - nz[2]);
        }
#pragma unroll
        for (int nt = 0; nt < 4; nt++) {
            acc[mt][nt] = __builtin_amdgcn_mfma_f32_16x16x32_bf16(Ap, Bp[nt], acc[mt][nt], 0, 0, 0);
            acc[mt][nt] = __builtin_amdgcn_mfma_f32_16x16x32_bf16(Ax, Bx[nt], acc[mt][nt], 0, 0, 0);
        }
    }
    float s_[4], q_[4];
#pragma unroll
    for (int nt = 0; nt < 4; nt++) { s_[nt] = 0.f; q_[nt] = 0.f; }
#pragma unroll
    for (int nt = 0; nt < 4; nt++) {
        const int ch = nt * 16 + l15;
        const float bs = bias[ch];
#pragma unroll
        for (int mt = 0; mt < 2; mt++) {
            const int pb = p0 + mt * 16 + quad * 4;
#pragma unroll
            for (int r = 0; r < 4; r++) {
                float x = acc[mt][nt][r] + bs;
                uint_t u = __float_as_uint(x);
                u += 0x7fffu + ((u >> 16) & 1u);
                Y[(size_t)(pb + r) * 64 + ch] = (ushort_t)(u >> 16);
                float v = __uint_as_float(u & 0xffff0000u);
                s_[nt] += v; q_[nt] += v * v;
            }
        }
    }
#pragma unroll
    for (int nt = 0; nt < 4; nt++) {
        s_[nt] += __shfl_xor(s_[nt], 16, 64); s_[nt] += __shfl_xor(s_[nt], 32, 64);
        q_[nt] += __shfl_xor(q_[nt], 16, 64); q_[nt] += __shfl_xor(q_[nt], 32, 64);
    }
    __shared__ float reds[4][4][16], redq[4][4][16];
    if (lane < 16) {
#pragma unroll
        for (int nt = 0; nt < 4; nt++) { reds[wid][nt][lane] = s_[nt]; redq[wid][nt][lane] = q_[nt]; }
    }
    __syncthreads();
    if (threadIdx.x < 16) {
#pragma unroll
        for (int nt = 0; nt < 4; nt++) {
            float ss = 0.f, qq = 0.f;
#pragma unroll
            for (int w = 0; w < 4; w++) { ss += reds[w][nt][threadIdx.x]; qq += redq[w][nt][threadIdx.x]; }
            atomicAdd(sums + nt * 16 + threadIdx.x, ss);
            atomicAdd(sq + nt * 16 + threadIdx.x, qq);
        }
    }
}

// ---------------------------------------------------------------- convN (MFMA, BN+ReLU on load, fused stats)
template <int IN, int OUT>
__global__ __launch_bounds__(256) void convN_mfma(const ushort_t* __restrict__ Yin,
                                                  const float* __restrict__ scale,
                                                  const float* __restrict__ shift,
                                                  const float* __restrict__ W,
                                                  const float* __restrict__ bias,
                                                  ushort_t* __restrict__ Yout,
                                                  float* __restrict__ sums,
                                                  float* __restrict__ sq) {
    constexpr int NT = OUT / 16;
    const int lane = threadIdx.x & 63, wid = threadIdx.x >> 6;
    const int l15 = lane & 15, quad = lane >> 4;
    const int p0 = blockIdx.x * 128 + wid * 32;

    float sc[2][8], sh[2][8];
#pragma unroll
    for (int kq = 0; kq < 2; kq++) {
        const int i0 = kq * 32 + quad * 8;
#pragma unroll
        for (int q = 0; q < 8; q++) { sc[kq][q] = scale[i0 + q]; sh[kq][q] = shift[i0 + q]; }
    }
    bf16x8 Bf[NT][2];
#pragma unroll
    for (int nt = 0; nt < NT; nt++)
#pragma unroll
        for (int kq = 0; kq < 2; kq++) {
            const float* wr = W + (size_t)(nt * 16 + l15) * IN + kq * 32 + quad * 8;
#pragma unroll
            for (int q = 0; q < 8; q++) Bf[nt][kq][q] = (short)f2bf(wr[q]);
        }

    bf16x8 Af[2][2];
#pragma unroll
    for (int mt = 0; mt < 2; mt++)
#pragma unroll
        for (int kq = 0; kq < 2; kq++) {
            const ushort_t* yr = Yin + (size_t)(p0 + mt * 16 + l15) * IN + kq * 32 + quad * 8;
            uint4 u = *(const uint4*)yr;
            float f[8]; unpack8(u, f);
#pragma unroll
            for (int q = 0; q < 8; q++) {
                float x = fmaxf(fmaf(f[q], sc[kq][q], sh[kq][q]), 0.f);
                Af[mt][kq][q] = (short)f2bf(x);
            }
        }

    f32x4 acc[2][NT];
#pragma unroll
    for (int mt = 0; mt < 2; mt++)
#pragma unroll
        for (int nt = 0; nt < NT; nt++) acc[mt][nt] = (f32x4){0.f, 0.f, 0.f, 0.f};
#pragma unroll
    for (int mt = 0; mt < 2; mt++)
#pragma unroll
        for (int nt = 0; nt < NT; nt++) {
            acc[mt][nt] = __builtin_amdgcn_mfma_f32_16x16x32_bf16(Af[mt][0], Bf[nt][0], acc[mt][nt], 0, 0, 0);
            acc[mt][nt] = __builtin_amdgcn_mfma_f32_16x16x32_bf16(Af[mt][1], Bf[nt][1], acc[mt][nt], 0, 0, 0);
        }
    float s_[NT], q_[NT];
#pragma unroll
    for (int nt = 0; nt < NT; nt++) { s_[nt] = 0.f; q_[nt] = 0.f; }
#pragma unroll
    for (int nt = 0; nt < NT; nt++) {
        const int ch = nt * 16 + l15;
        const float bs = bias[ch];
#pragma unroll
        for (int mt = 0; mt < 2; mt++) {
            const int pb = p0 + mt * 16 + quad * 4;
#pragma unroll
            for (int r = 0; r < 4; r++) {
                float x = acc[mt][nt][r] + bs;
                uint_t u = __float_as_uint(x);
                u += 0x7fffu + ((u >> 16) & 1u);
                Yout[(size_t)(pb + r) * OUT + ch] = (ushort_t)(u >> 16);
                float v = __uint_as_float(u & 0xffff0000u);
                s_[nt] += v; q_[nt] += v * v;
            }
        }
    }
#pragma unroll
    for (int nt = 0; nt < NT; nt++) {
        s_[nt] += __shfl_xor(s_[nt], 16, 64); s_[nt] += __shfl_xor(s_[nt], 32, 64);
        q_[nt] += __shfl_xor(q_[nt], 16, 64); q_[nt] += __shfl_xor(q_[nt], 32, 64);
    }
    __shared__ float reds[4][NT][16], redq[4][NT][16];
    if (lane < 16) {
#pragma unroll
        for (int nt = 0; nt < NT; nt++) { reds[wid][nt][lane] = s_[nt]; redq[wid][nt][lane] = q_[nt]; }
    }
    __syncthreads();
    if (threadIdx.x < 16) {
#pragma unroll
        for (int nt = 0; nt < NT; nt++) {
            float ss = 0.f, qq = 0.f;
#pragma unroll
            for (int w = 0; w < 4; w++) { ss += reds[w][nt][threadIdx.x]; qq += redq[w][nt][threadIdx.x]; }
            atomicAdd(sums + nt * 16 + threadIdx.x, ss);
            atomicAdd(sq + nt * 16 + threadIdx.x, qq);
        }
    }
}

// ---------------------------------------------------------------- finalize BN params
__global__ void finalize_kernel(const float* __restrict__ sums, const float* __restrict__ sq,
                                const float* __restrict__ g, const float* __restrict__ be,
                                float* __restrict__ scale, float* __restrict__ shift, int OUT) {
    int c = threadIdx.x;
    if (c < OUT) {
        float mean = sums[c] * (1.f / (float)NPOS);
        float var = sq[c] * (1.f / (float)NPOS) - mean * mean;
        float inv = 1.f / sqrtf(var + EPSV);
        float sc = g[c] * inv;
        scale[c] = sc;
        shift[c] = be[c] - mean * sc;
    }
}

// ---------------------------------------------------------------- BN3 + ReLU + max over k
__global__ __launch_bounds__(256) void final_kernel(const ushort_t* __restrict__ Y3,
                                                    const float* __restrict__ scale,
                                                    const float* __restrict__ shift,
                                                    float* __restrict__ out) {
    const int b = blockIdx.x >> 5;
    const int stile = (blockIdx.x & 31) * 32;
    const int sl = threadIdx.x >> 3;
    const int oc = threadIdx.x & 7;
    const int s = stile + sl;
    const size_t base = ((size_t)(b * NPOINT + s)) * 32 * 128 + oc * 16;
    float vmax[16];
#pragma unroll
    for (int i = 0; i < 16; i++) vmax[i] = 0.f;
    for (int k = 0; k < 32; k++) {
        const ushort_t* yp = Y3 + base + (size_t)k * 128;
#pragma unroll
        for (int h = 0; h < 2; h++) {
            uint4 u = *(const uint4*)(yp + h * 8);
            float f[8];
            unpack8(u, f);
#pragma unroll
            for (int i = 0; i < 8; i++) {
                int o = oc * 16 + h * 8 + i;
                float v = fmaf(f[i], scale[o], shift[o]);
                vmax[h * 8 + i] = fmaxf(vmax[h * 8 + i], v);
            }
        }
    }
    __shared__ float res[32][130];
#pragma unroll
    for (int i = 0; i < 16; i++) res[sl][oc * 16 + i] = vmax[i];
    __syncthreads();
    const int so = threadIdx.x & 31;
    const int og = threadIdx.x >> 5;
#pragma unroll
    for (int r = 0; r < 16; r++) {
        int o = og * 16 + r;
        out[((size_t)(b * 128 + o)) * NPOINT + stile + so] = res[so][o];
    }
}

// ---------------------------------------------------------------- launch
extern "C" void kernel_launch(void* const* d_in, const int* in_sizes, int n_in,
                              void* d_out, int out_size, void* d_ws, size_t ws_size,
                              hipStream_t stream) {
    const float* xyz = (const float*)d_in[0];
    const float* points = (const float*)d_in[1];
    const float* w0 = (const float*)d_in[2];
    const float* b0 = (const float*)d_in[3];
    const float* g0 = (const float*)d_in[4];
    const float* be0 = (const float*)d_in[5];
    const float* w1 = (const float*)d_in[6];
    const float* b1 = (const float*)d_in[7];
    const float* g1 = (const float*)d_in[8];
    const float* be1 = (const float*)d_in[9];
    const float* w2 = (const float*)d_in[10];
    const float* b2 = (const float*)d_in[11];
    const float* g2 = (const float*)d_in[12];
    const float* be2 = (const float*)d_in[13];

    float* out = (float*)d_out;
    float* new_xyz = out;                      // B*NPOINT*3 = 49152
    float* final_out = out + BATCH * NPOINT * 3;

    // workspace layout (194 MiB; Y3 overlays Y1 -- Y1 dead after conv2)
    char* ws = (char*)d_ws;
    const size_t MB = 1024u * 1024u;
    const size_t o_gidx = 0;
    const size_t o_y2 = 2 * MB;
    const size_t o_y13 = o_y2 + (size_t)NPOS * 64 * 2;
    const size_t o_stats = o_y13 + (size_t)NPOS * 128 * 2;
    const size_t o_params = o_stats + 2048;

    int* gidx = (int*)(ws + o_gidx);
    ushort_t* Y1 = (ushort_t*)(ws + o_y13);
    ushort_t* Y2 = (ushort_t*)(ws + o_y2);
    ushort_t* Y3 = (ushort_t*)(ws + o_y13);
    float* st = (float*)(ws + o_stats);
    float* sum1 = st + 0, *sq1 = st + 64;
    float* sum2 = st + 128, *sq2 = st + 192;
    float* sum3 = st + 256, *sq3 = st + 384;
    float* pr = (float*)(ws + o_params);
    float* scale1 = pr + 0, *shift1 = pr + 64;
    float* scale2 = pr + 128, *shift2 = pr + 192;
    float* scale3 = pr + 256, *shift3 = pr + 384;

    zero_kernel<<<1, 512, 0, stream>>>(st, 512);

    fps_kernel<<<BATCH, 256, 0, stream>>>(xyz, new_xyz);
    ballq_kernel<<<(BATCH * NPOINT) / 4, 256, 0, stream>>>(xyz, new_xyz, gidx);
    conv1_mfma<<<NPOS / 128, 256, 0, stream>>>(xyz, points, new_xyz, gidx, w0, b0, Y1, sum1, sq1);
    finalize_kernel<<<1, 128, 0, stream>>>(sum1, sq1, g0, be0, scale1, shift1, 64);
    convN_mfma<64, 64><<<NPOS / 128, 256, 0, stream>>>(Y1, scale1, shift1, w1, b1, Y2, sum2, sq2);
    finalize_kernel<<<1, 128, 0, stream>>>(sum2, sq2, g1, be1, scale2, shift2, 64);
    convN_mfma<64, 128><<<NPOS / 128, 256, 0, stream>>>(Y2, scale2, shift2, w2, b2, Y3, sum3, sq3);
    finalize_kernel<<<1, 128, 0, stream>>>(sum3, sq3, g2, be2, scale3, shift3, 128);
    final_kernel<<<BATCH * 32, 256, 0, stream>>>(Y3, scale3, shift3, final_out);
}

// Round 6
// 1047.608 us; speedup vs baseline: 1.0622x; 1.0622x over previous
//
#include <hip/hip_runtime.h>
#include <stdint.h>

#pragma clang fp contract(off)

#define BATCH   16
#define NPTS    4096
#define NPOINT  1024
#define NSAMPLE 32
#define NPOS    (BATCH*NPOINT*NSAMPLE)   // 524288
#define NBLK    (NPOS/128)               // 4096 conv blocks
#define EPSV    1e-5f

typedef unsigned short ushort_t;
typedef unsigned int uint_t;
typedef unsigned long long u64;
typedef __attribute__((ext_vector_type(8))) short bf16x8;
typedef __attribute__((ext_vector_type(4))) float f32x4;
typedef __attribute__((ext_vector_type(2))) float f32x2;

__device__ inline ushort_t f2bf(float f) {
    uint_t u = __float_as_uint(f);
    u += 0x7fffu + ((u >> 16) & 1u);   // RNE (no NaNs in this workload)
    return (ushort_t)(u >> 16);
}
__device__ inline void unpack8(uint4 u, float* f) {
    f[0] = __uint_as_float(u.x << 16); f[1] = __uint_as_float(u.x & 0xffff0000u);
    f[2] = __uint_as_float(u.y << 16); f[3] = __uint_as_float(u.y & 0xffff0000u);
    f[4] = __uint_as_float(u.z << 16); f[5] = __uint_as_float(u.z & 0xffff0000u);
    f[6] = __uint_as_float(u.w << 16); f[7] = __uint_as_float(u.w & 0xffff0000u);
}

// ---------------------------------------------------------------- FPS
// One block per batch, 512 threads (8 waves), 8 pts/thread as 4 float2
// pairs (v_pk_* fp32). Packed-u64 tree -> DPP wave reduce -> parity-LDS
// cross-wave reduce with ONE barrier. Exact fp32 op order (contract off).
#define DPP_MAX_STAGE(CTRL) do {                                              \
    uint_t _lo2 = __builtin_amdgcn_update_dpp(lo, lo, CTRL, 0xf, 0xf, false); \
    uint_t _hi2 = __builtin_amdgcn_update_dpp(hi, hi, CTRL, 0xf, 0xf, false); \
    u64 _o = ((u64)_hi2 << 32) | _lo2;                                        \
    u64 _v = ((u64)hi << 32) | lo;                                            \
    bool _g = _o > _v;                                                        \
    lo = _g ? _lo2 : lo; hi = _g ? _hi2 : hi;                                 \
} while (0)

__global__ __launch_bounds__(512) void fps_kernel(const float* __restrict__ xyz,
                                                  float* __restrict__ new_xyz) {
    __shared__ float4 lxyz[NPTS];     // 64 KiB
    __shared__ u64 wbest[2][8];
    __shared__ int fpsidx[NPOINT];
    const int b = blockIdx.x;
    const int tid = threadIdx.x;
    const float* base = xyz + (size_t)b * NPTS * 3;
    for (int n = tid; n < NPTS; n += 512) {
        lxyz[n] = make_float4(base[3 * n], base[3 * n + 1], base[3 * n + 2], 0.f);
    }
    __syncthreads();

    f32x2 px[4], py[4], pz[4], dist[4];
    uint_t lowc[8];   // ~idx, iteration-invariant (smaller idx wins ties)
#pragma unroll
    for (int j = 0; j < 4; j++) {
        float4 v0 = lxyz[tid + (2 * j) * 512];
        float4 v1 = lxyz[tid + (2 * j + 1) * 512];
        px[j] = (f32x2){v0.x, v1.x};
        py[j] = (f32x2){v0.y, v1.y};
        pz[j] = (f32x2){v0.z, v1.z};
        dist[j] = (f32x2){1e10f, 1e10f};
        lowc[2 * j] = ~(uint_t)(tid + (2 * j) * 512);
        lowc[2 * j + 1] = ~(uint_t)(tid + (2 * j + 1) * 512);
    }
    if (tid == 0) fpsidx[0] = 0;
    int cur = 0;
    const int lane = tid & 63, wid = tid >> 6;

    for (int it = 1; it < NPOINT; ++it) {
        float4 c = lxyz[cur];
        const f32x2 cx = (f32x2){c.x, c.x};
        const f32x2 cy = (f32x2){c.y, c.y};
        const f32x2 cz = (f32x2){c.z, c.z};
        u64 t[4];
#pragma unroll
        for (int j = 0; j < 4; j++) {
            f32x2 dx = px[j] - cx;
            f32x2 dy = py[j] - cy;
            f32x2 dz = pz[j] - cz;
            f32x2 d = (dx * dx + dy * dy) + dz * dz;   // contract OFF
            f32x2 nd = __builtin_elementwise_min(dist[j], d);
            dist[j] = nd;
            u64 e0 = ((u64)__float_as_uint(nd.x) << 32) | lowc[2 * j];
            u64 e1 = ((u64)__float_as_uint(nd.y) << 32) | lowc[2 * j + 1];
            t[j] = e0 > e1 ? e0 : e1;
        }
        t[0] = t[0] > t[1] ? t[0] : t[1];
        t[2] = t[2] > t[3] ? t[2] : t[3];
        u64 v = t[0] > t[2] ? t[0] : t[2];

        uint_t lo = (uint_t)v, hi = (uint_t)(v >> 32);
        DPP_MAX_STAGE(0x111);   // row_shr:1
        DPP_MAX_STAGE(0x112);   // row_shr:2
        DPP_MAX_STAGE(0x114);   // row_shr:4
        DPP_MAX_STAGE(0x118);   // row_shr:8
        DPP_MAX_STAGE(0x142);   // row_bcast:15
        DPP_MAX_STAGE(0x143);   // row_bcast:31
        uint_t mlo = __builtin_amdgcn_readlane(lo, 63);
        uint_t mhi = __builtin_amdgcn_readlane(hi, 63);

        const int par = it & 1;
        if (lane == 0) wbest[par][wid] = ((u64)mhi << 32) | mlo;
        __syncthreads();
        u64 w0 = wbest[par][0], w1 = wbest[par][1];
        u64 w2 = wbest[par][2], w3 = wbest[par][3];
        u64 w4 = wbest[par][4], w5 = wbest[par][5];
        u64 w6 = wbest[par][6], w7 = wbest[par][7];
        u64 a0 = w0 > w1 ? w0 : w1;
        u64 a1 = w2 > w3 ? w2 : w3;
        u64 a2 = w4 > w5 ? w4 : w5;
        u64 a3 = w6 > w7 ? w6 : w7;
        a0 = a0 > a1 ? a0 : a1;
        a2 = a2 > a3 ? a2 : a3;
        u64 bb = a0 > a2 ? a0 : a2;
        cur = (int)(~(uint_t)bb) & (NPTS - 1);
        if (tid == 0) fpsidx[it] = cur;
        // parity buffering: next write to this slot is 2 barriers away -> safe
    }
    __syncthreads();
    float* ob = new_xyz + (size_t)b * NPOINT * 3;
    for (int s = tid; s < NPOINT; s += 512) {
        float4 v = lxyz[fpsidx[s]];
        ob[3 * s + 0] = v.x; ob[3 * s + 1] = v.y; ob[3 * s + 2] = v.z;
    }
}

// ---------------------------------------------------------------- ball query
__global__ __launch_bounds__(256) void ballq_kernel(const float* __restrict__ xyz,
                                                    const float* __restrict__ new_xyz,
                                                    int* __restrict__ gidx) {
    const int gw = (int)((blockIdx.x * 256 + threadIdx.x) >> 6);
    const int lane = threadIdx.x & 63;
    const int b = gw / NPOINT, s = gw % NPOINT;
    const float* nb = new_xyz + ((size_t)b * NPOINT + s) * 3;
    const float cx = nb[0], cy = nb[1], cz = nb[2];
    const float* xb = xyz + (size_t)b * NPTS * 3;
    const float r2 = (float)(0.2 * 0.2);
    int cnt = 0;
    int first = -1;
    int* out = gidx + (size_t)gw * NSAMPLE;
    for (int j0 = 0; j0 < NPTS; j0 += 64) {
        int j = j0 + lane;
        float dx = __fsub_rn(xb[j * 3 + 0], cx);
        float dy = __fsub_rn(xb[j * 3 + 1], cy);
        float dz = __fsub_rn(xb[j * 3 + 2], cz);
        float d = __fadd_rn(__fadd_rn(__fmul_rn(dx, dx), __fmul_rn(dy, dy)),
                            __fmul_rn(dz, dz));
        bool pred = !(d > r2);
        u64 mask = __ballot(pred);
        if (first < 0 && mask != 0ull) first = j0 + (__ffsll((long long)mask) - 1);
        int before = __popcll(mask & ((1ull << lane) - 1ull));
        int slot = cnt + before;
        if (pred && slot < NSAMPLE) out[slot] = j;
        cnt += (int)__popcll(mask);
        if (cnt >= NSAMPLE) break;
    }
    if (cnt < NSAMPLE) {
        if (lane >= cnt && lane < NSAMPLE) out[lane] = first;
    }
}

// ---------------------------------------------------------------- conv1 (MFMA + partial stats)
// 128 positions/block, 4 waves x 32 pos (2 m-tiles). Epilogue: bf16-round,
// store Y, block-reduce sum/sumsq -> PLAIN STORES of per-block partials
// (no atomics; reduce_finalize sums them).
__global__ __launch_bounds__(256) void conv1_mfma(const float* __restrict__ xyz,
                                                  const float* __restrict__ points,
                                                  const float* __restrict__ new_xyz,
                                                  const int* __restrict__ gidx,
                                                  const float* __restrict__ W,
                                                  const float* __restrict__ bias,
                                                  ushort_t* __restrict__ Y,
                                                  float* __restrict__ part_s,
                                                  float* __restrict__ part_q) {
    const int lane = threadIdx.x & 63, wid = threadIdx.x >> 6;
    const int l15 = lane & 15, quad = lane >> 4;
    const int p0 = blockIdx.x * 128 + wid * 32;

    bf16x8 Bp[4], Bx[4];
#pragma unroll
    for (int nt = 0; nt < 4; nt++) {
        const float* wr = W + (size_t)(nt * 16 + l15) * 35;
#pragma unroll
        for (int q = 0; q < 8; q++) Bp[nt][q] = (short)f2bf(wr[3 + quad * 8 + q]);
#pragma unroll
        for (int q = 0; q < 8; q++)
            Bx[nt][q] = (quad == 0 && q < 3) ? (short)f2bf(wr[q]) : (short)0;
    }
    f32x4 acc[2][4];
#pragma unroll
    for (int mt = 0; mt < 2; mt++)
#pragma unroll
        for (int nt = 0; nt < 4; nt++) acc[mt][nt] = (f32x4){0.f, 0.f, 0.f, 0.f};

#pragma unroll
    for (int mt = 0; mt < 2; mt++) {
        const int p = p0 + mt * 16 + l15;
        const int b = p >> 15, s = (p & 32767) >> 5;
        const int j = gidx[p];
        const float* pr = points + ((size_t)(b * NPTS + j)) * 32 + quad * 8;
        bf16x8 Ap, Ax;
#pragma unroll
        for (int q = 0; q < 8; q++) Ap[q] = (short)f2bf(pr[q]);
#pragma unroll
        for (int q = 0; q < 8; q++) Ax[q] = 0;
        const float* xp = xyz + ((size_t)(b * NPTS + j)) * 3;
        const float* nz = new_xyz + ((size_t)(b * NPOINT + s)) * 3;
        if (quad == 0) {
            Ax[0] = (short)f2bf(xp[0] - nz[0]);
            Ax[1] = (short)f2bf(xp[1] - nz[1]);
            Ax[2] = (short)f2bf(xp[2] - nz[2]);
        }
#pragma unroll
        for (int nt = 0; nt < 4; nt++) {
            acc[mt][nt] = __builtin_amdgcn_mfma_f32_16x16x32_bf16(Ap, Bp[nt], acc[mt][nt], 0, 0, 0);
            acc[mt][nt] = __builtin_amdgcn_mfma_f32_16x16x32_bf16(Ax, Bx[nt], acc[mt][nt], 0, 0, 0);
        }
    }
    float s_[4], q_[4];
#pragma unroll
    for (int nt = 0; nt < 4; nt++) { s_[nt] = 0.f; q_[nt] = 0.f; }
#pragma unroll
    for (int nt = 0; nt < 4; nt++) {
        const int ch = nt * 16 + l15;
        const float bs = bias[ch];
#pragma unroll
        for (int mt = 0; mt < 2; mt++) {
            const int pb = p0 + mt * 16 + quad * 4;
#pragma unroll
            for (int r = 0; r < 4; r++) {
                float x = acc[mt][nt][r] + bs;
                uint_t u = __float_as_uint(x);
                u += 0x7fffu + ((u >> 16) & 1u);
                Y[(size_t)(pb + r) * 64 + ch] = (ushort_t)(u >> 16);
                float v = __uint_as_float(u & 0xffff0000u);
                s_[nt] += v; q_[nt] += v * v;
            }
        }
    }
#pragma unroll
    for (int nt = 0; nt < 4; nt++) {
        s_[nt] += __shfl_xor(s_[nt], 16, 64); s_[nt] += __shfl_xor(s_[nt], 32, 64);
        q_[nt] += __shfl_xor(q_[nt], 16, 64); q_[nt] += __shfl_xor(q_[nt], 32, 64);
    }
    __shared__ float reds[4][4][16], redq[4][4][16];
    if (lane < 16) {
#pragma unroll
        for (int nt = 0; nt < 4; nt++) { reds[wid][nt][lane] = s_[nt]; redq[wid][nt][lane] = q_[nt]; }
    }
    __syncthreads();
    if (threadIdx.x < 16) {
#pragma unroll
        for (int nt = 0; nt < 4; nt++) {
            float ss = 0.f, qq = 0.f;
#pragma unroll
            for (int w = 0; w < 4; w++) { ss += reds[w][nt][threadIdx.x]; qq += redq[w][nt][threadIdx.x]; }
            const int ch = nt * 16 + threadIdx.x;
            part_s[(size_t)ch * NBLK + blockIdx.x] = ss;
            part_q[(size_t)ch * NBLK + blockIdx.x] = qq;
        }
    }
}

// ---------------------------------------------------------------- convN (MFMA, BN+ReLU on load, partial stats)
template <int IN, int OUT>
__global__ __launch_bounds__(256) void convN_mfma(const ushort_t* __restrict__ Yin,
                                                  const float* __restrict__ scale,
                                                  const float* __restrict__ shift,
                                                  const float* __restrict__ W,
                                                  const float* __restrict__ bias,
                                                  ushort_t* __restrict__ Yout,
                                                  float* __restrict__ part_s,
                                                  float* __restrict__ part_q) {
    constexpr int NT = OUT / 16;
    const int lane = threadIdx.x & 63, wid = threadIdx.x >> 6;
    const int l15 = lane & 15, quad = lane >> 4;
    const int p0 = blockIdx.x * 128 + wid * 32;

    float sc[2][8], sh[2][8];
#pragma unroll
    for (int kq = 0; kq < 2; kq++) {
        const int i0 = kq * 32 + quad * 8;
#pragma unroll
        for (int q = 0; q < 8; q++) { sc[kq][q] = scale[i0 + q]; sh[kq][q] = shift[i0 + q]; }
    }
    bf16x8 Bf[NT][2];
#pragma unroll
    for (int nt = 0; nt < NT; nt++)
#pragma unroll
        for (int kq = 0; kq < 2; kq++) {
            const float* wr = W + (size_t)(nt * 16 + l15) * IN + kq * 32 + quad * 8;
#pragma unroll
            for (int q = 0; q < 8; q++) Bf[nt][kq][q] = (short)f2bf(wr[q]);
        }

    bf16x8 Af[2][2];
#pragma unroll
    for (int mt = 0; mt < 2; mt++)
#pragma unroll
        for (int kq = 0; kq < 2; kq++) {
            const ushort_t* yr = Yin + (size_t)(p0 + mt * 16 + l15) * IN + kq * 32 + quad * 8;
            uint4 u = *(const uint4*)yr;
            float f[8]; unpack8(u, f);
#pragma unroll
            for (int q = 0; q < 8; q++) {
                float x = fmaxf(fmaf(f[q], sc[kq][q], sh[kq][q]), 0.f);
                Af[mt][kq][q] = (short)f2bf(x);
            }
        }

    f32x4 acc[2][NT];
#pragma unroll
    for (int mt = 0; mt < 2; mt++)
#pragma unroll
        for (int nt = 0; nt < NT; nt++) acc[mt][nt] = (f32x4){0.f, 0.f, 0.f, 0.f};
#pragma unroll
    for (int mt = 0; mt < 2; mt++)
#pragma unroll
        for (int nt = 0; nt < NT; nt++) {
            acc[mt][nt] = __builtin_amdgcn_mfma_f32_16x16x32_bf16(Af[mt][0], Bf[nt][0], acc[mt][nt], 0, 0, 0);
            acc[mt][nt] = __builtin_amdgcn_mfma_f32_16x16x32_bf16(Af[mt][1], Bf[nt][1], acc[mt][nt], 0, 0, 0);
        }
    float s_[NT], q_[NT];
#pragma unroll
    for (int nt = 0; nt < NT; nt++) { s_[nt] = 0.f; q_[nt] = 0.f; }
#pragma unroll
    for (int nt = 0; nt < NT; nt++) {
        const int ch = nt * 16 + l15;
        const float bs = bias[ch];
#pragma unroll
        for (int mt = 0; mt < 2; mt++) {
            const int pb = p0 + mt * 16 + quad * 4;
#pragma unroll
            for (int r = 0; r < 4; r++) {
                float x = acc[mt][nt][r] + bs;
                uint_t u = __float_as_uint(x);
                u += 0x7fffu + ((u >> 16) & 1u);
                Yout[(size_t)(pb + r) * OUT + ch] = (ushort_t)(u >> 16);
                float v = __uint_as_float(u & 0xffff0000u);
                s_[nt] += v; q_[nt] += v * v;
            }
        }
    }
#pragma unroll
    for (int nt = 0; nt < NT; nt++) {
        s_[nt] += __shfl_xor(s_[nt], 16, 64); s_[nt] += __shfl_xor(s_[nt], 32, 64);
        q_[nt] += __shfl_xor(q_[nt], 16, 64); q_[nt] += __shfl_xor(q_[nt], 32, 64);
    }
    __shared__ float reds[4][NT][16], redq[4][NT][16];
    if (lane < 16) {
#pragma unroll
        for (int nt = 0; nt < NT; nt++) { reds[wid][nt][lane] = s_[nt]; redq[wid][nt][lane] = q_[nt]; }
    }
    __syncthreads();
    if (threadIdx.x < 16) {
#pragma unroll
        for (int nt = 0; nt < NT; nt++) {
            float ss = 0.f, qq = 0.f;
#pragma unroll
            for (int w = 0; w < 4; w++) { ss += reds[w][nt][threadIdx.x]; qq += redq[w][nt][threadIdx.x]; }
            const int ch = nt * 16 + threadIdx.x;
            part_s[(size_t)ch * NBLK + blockIdx.x] = ss;
            part_q[(size_t)ch * NBLK + blockIdx.x] = qq;
        }
    }
}

// ---------------------------------------------------------------- reduce partials -> BN scale/shift
// One block per channel; coalesced read of 4096 partials.
__global__ __launch_bounds__(256) void reduce_finalize(const float* __restrict__ part_s,
                                                       const float* __restrict__ part_q,
                                                       const float* __restrict__ g,
                                                       const float* __restrict__ be,
                                                       float* __restrict__ scale,
                                                       float* __restrict__ shift) {
    const int ch = blockIdx.x;
    const float* p1 = part_s + (size_t)ch * NBLK;
    const float* p2 = part_q + (size_t)ch * NBLK;
    float s = 0.f, q = 0.f;
    for (int i = threadIdx.x; i < NBLK; i += 256) { s += p1[i]; q += p2[i]; }
#pragma unroll
    for (int m = 1; m < 64; m <<= 1) { s += __shfl_xor(s, m, 64); q += __shfl_xor(q, m, 64); }
    __shared__ float ls[4], lq[4];
    const int lane = threadIdx.x & 63, wid = threadIdx.x >> 6;
    if (lane == 0) { ls[wid] = s; lq[wid] = q; }
    __syncthreads();
    if (threadIdx.x == 0) {
        float ssum = ls[0] + ls[1] + ls[2] + ls[3];
        float qsum = lq[0] + lq[1] + lq[2] + lq[3];
        float mean = ssum * (1.f / (float)NPOS);
        float var = qsum * (1.f / (float)NPOS) - mean * mean;
        float inv = 1.f / sqrtf(var + EPSV);
        float sc = g[ch] * inv;
        scale[ch] = sc;
        shift[ch] = be[ch] - mean * sc;
    }
}

// ---------------------------------------------------------------- BN3 + ReLU + max over k
__global__ __launch_bounds__(256) void final_kernel(const ushort_t* __restrict__ Y3,
                                                    const float* __restrict__ scale,
                                                    const float* __restrict__ shift,
                                                    float* __restrict__ out) {
    const int b = blockIdx.x >> 5;
    const int stile = (blockIdx.x & 31) * 32;
    const int sl = threadIdx.x >> 3;
    const int oc = threadIdx.x & 7;
    const int s = stile + sl;
    const size_t base = ((size_t)(b * NPOINT + s)) * 32 * 128 + oc * 16;
    float vmax[16];
#pragma unroll
    for (int i = 0; i < 16; i++) vmax[i] = 0.f;
    for (int k = 0; k < 32; k++) {
        const ushort_t* yp = Y3 + base + (size_t)k * 128;
#pragma unroll
        for (int h = 0; h < 2; h++) {
            uint4 u = *(const uint4*)(yp + h * 8);
            float f[8];
            unpack8(u, f);
#pragma unroll
            for (int i = 0; i < 8; i++) {
                int o = oc * 16 + h * 8 + i;
                float v = fmaf(f[i], scale[o], shift[o]);
                vmax[h * 8 + i] = fmaxf(vmax[h * 8 + i], v);
            }
        }
    }
    __shared__ float res[32][130];
#pragma unroll
    for (int i = 0; i < 16; i++) res[sl][oc * 16 + i] = vmax[i];
    __syncthreads();
    const int so = threadIdx.x & 31;
    const int og = threadIdx.x >> 5;
#pragma unroll
    for (int r = 0; r < 16; r++) {
        int o = og * 16 + r;
        out[((size_t)(b * 128 + o)) * NPOINT + stile + so] = res[so][o];
    }
}

// ---------------------------------------------------------------- launch
extern "C" void kernel_launch(void* const* d_in, const int* in_sizes, int n_in,
                              void* d_out, int out_size, void* d_ws, size_t ws_size,
                              hipStream_t stream) {
    const float* xyz = (const float*)d_in[0];
    const float* points = (const float*)d_in[1];
    const float* w0 = (const float*)d_in[2];
    const float* b0 = (const float*)d_in[3];
    const float* g0 = (const float*)d_in[4];
    const float* be0 = (const float*)d_in[5];
    const float* w1 = (const float*)d_in[6];
    const float* b1 = (const float*)d_in[7];
    const float* g1 = (const float*)d_in[8];
    const float* be1 = (const float*)d_in[9];
    const float* w2 = (const float*)d_in[10];
    const float* b2 = (const float*)d_in[11];
    const float* g2 = (const float*)d_in[12];
    const float* be2 = (const float*)d_in[13];

    float* out = (float*)d_out;
    float* new_xyz = out;                      // B*NPOINT*3 = 49152
    float* final_out = out + BATCH * NPOINT * 3;

    // workspace layout (~198 MiB; Y3 overlays Y1 -- Y1 dead after conv2)
    char* ws = (char*)d_ws;
    const size_t MB = 1024u * 1024u;
    const size_t o_gidx = 0;
    const size_t o_y2 = 2 * MB;
    const size_t o_y13 = o_y2 + (size_t)NPOS * 64 * 2;
    const size_t o_params = o_y13 + (size_t)NPOS * 128 * 2;   // 512 floats
    const size_t o_parts = o_params + 4096;                   // 2 x 128*4096 floats

    int* gidx = (int*)(ws + o_gidx);
    ushort_t* Y1 = (ushort_t*)(ws + o_y13);
    ushort_t* Y2 = (ushort_t*)(ws + o_y2);
    ushort_t* Y3 = (ushort_t*)(ws + o_y13);
    float* pr = (float*)(ws + o_params);
    float* scale1 = pr + 0, *shift1 = pr + 64;
    float* scale2 = pr + 128, *shift2 = pr + 192;
    float* scale3 = pr + 256, *shift3 = pr + 384;
    float* part_s = (float*)(ws + o_parts);
    float* part_q = part_s + (size_t)128 * NBLK;

    fps_kernel<<<BATCH, 512, 0, stream>>>(xyz, new_xyz);
    ballq_kernel<<<(BATCH * NPOINT) / 4, 256, 0, stream>>>(xyz, new_xyz, gidx);
    conv1_mfma<<<NBLK, 256, 0, stream>>>(xyz, points, new_xyz, gidx, w0, b0, Y1, part_s, part_q);
    reduce_finalize<<<64, 256, 0, stream>>>(part_s, part_q, g0, be0, scale1, shift1);
    convN_mfma<64, 64><<<NBLK, 256, 0, stream>>>(Y1, scale1, shift1, w1, b1, Y2, part_s, part_q);
    reduce_finalize<<<64, 256, 0, stream>>>(part_s, part_q, g1, be1, scale2, shift2);
    convN_mfma<64, 128><<<NBLK, 256, 0, stream>>>(Y2, scale2, shift2, w2, b2, Y3, part_s, part_q);
    reduce_finalize<<<128, 256, 0, stream>>>(part_s, part_q, g2, be2, scale3, shift3);
    final_kernel<<<BATCH * 32, 256, 0, stream>>>(Y3, scale3, shift3, final_out);
}

// Round 7
// 909.575 us; speedup vs baseline: 1.2234x; 1.1518x over previous
//
#include <hip/hip_runtime.h>
#include <hip/hip_bf16.h>
#include <stdint.h>

#pragma clang fp contract(off)

#define BATCH   16
#define NPTS    4096
#define NPOINT  1024
#define NSAMPLE 32
#define NPOS    (BATCH*NPOINT*NSAMPLE)   // 524288
#define NBLK    (NPOS/128)               // 4096 conv blocks
#define EPSV    1e-5f

typedef unsigned short ushort_t;
typedef unsigned int uint_t;
typedef unsigned long long u64;
typedef __attribute__((ext_vector_type(8))) short bf16x8;
typedef __attribute__((ext_vector_type(4))) float f32x4;
typedef __attribute__((ext_vector_type(2))) float f32x2;

__device__ inline ushort_t f2bf(float f) {
    uint_t u = __float_as_uint(f);
    u += 0x7fffu + ((u >> 16) & 1u);   // RNE
    return (ushort_t)(u >> 16);
}
// packed fp32 pair -> packed bf16 (RNE, v_cvt_pk_bf16_f32)
__device__ inline uint_t pkbf(float a, float b) {
    __hip_bfloat162 h = __float22bfloat162_rn(make_float2(a, b));
    uint_t r; __builtin_memcpy(&r, &h, 4); return r;
}
__device__ inline bf16x8 asbf(uint4 u) {
    bf16x8 v; __builtin_memcpy(&v, &u, 16); return v;
}
__device__ inline void unpack8(uint4 u, float* f) {
    f[0] = __uint_as_float(u.x << 16); f[1] = __uint_as_float(u.x & 0xffff0000u);
    f[2] = __uint_as_float(u.y << 16); f[3] = __uint_as_float(u.y & 0xffff0000u);
    f[4] = __uint_as_float(u.z << 16); f[5] = __uint_as_float(u.z & 0xffff0000u);
    f[6] = __uint_as_float(u.w << 16); f[7] = __uint_as_float(u.w & 0xffff0000u);
}

// ---------------------------------------------------------------- weight prep (fp32 -> bf16, frag order)
__global__ __launch_bounds__(256) void prep_w(const float* __restrict__ w0,
                                              const float* __restrict__ w1,
                                              const float* __restrict__ w2,
                                              ushort_t* __restrict__ Wp0,
                                              ushort_t* __restrict__ Wx0,
                                              ushort_t* __restrict__ Wp1,
                                              ushort_t* __restrict__ Wp2) {
    const int t = blockIdx.x * 256 + threadIdx.x;
    const int stride = gridDim.x * 256;
    for (int i = t; i < 64 * 32; i += stride) { int ch = i >> 5, k = i & 31; Wp0[i] = f2bf(w0[ch * 35 + 3 + k]); }
    for (int i = t; i < 64 * 4;  i += stride) { int ch = i >> 2, q = i & 3;  Wx0[i] = (q < 3) ? f2bf(w0[ch * 35 + q]) : (ushort_t)0; }
    for (int i = t; i < 64 * 64; i += stride) Wp1[i] = f2bf(w1[i]);
    for (int i = t; i < 128 * 64; i += stride) Wp2[i] = f2bf(w2[i]);
}

// ---------------------------------------------------------------- FPS (R5 256-thread version)
#define DPP_MAX_STAGE(CTRL) do {                                              \
    uint_t _lo2 = __builtin_amdgcn_update_dpp(lo, lo, CTRL, 0xf, 0xf, false); \
    uint_t _hi2 = __builtin_amdgcn_update_dpp(hi, hi, CTRL, 0xf, 0xf, false); \
    u64 _o = ((u64)_hi2 << 32) | _lo2;                                        \
    u64 _v = ((u64)hi << 32) | lo;                                            \
    bool _g = _o > _v;                                                        \
    lo = _g ? _lo2 : lo; hi = _g ? _hi2 : hi;                                 \
} while (0)

__global__ __launch_bounds__(256) void fps_kernel(const float* __restrict__ xyz,
                                                  float* __restrict__ new_xyz) {
    __shared__ float4 lxyz[NPTS];     // 64 KiB
    __shared__ u64 wbest[2][4];
    __shared__ int fpsidx[NPOINT];
    const int b = blockIdx.x;
    const int tid = threadIdx.x;
    const float* base = xyz + (size_t)b * NPTS * 3;
    for (int n = tid; n < NPTS; n += 256) {
        lxyz[n] = make_float4(base[3 * n], base[3 * n + 1], base[3 * n + 2], 0.f);
    }
    __syncthreads();

    f32x2 px[8], py[8], pz[8], dist[8];
    uint_t lowc[16];   // ~idx, iteration-invariant (smaller idx wins ties)
#pragma unroll
    for (int j = 0; j < 8; j++) {
        float4 v0 = lxyz[tid + (2 * j) * 256];
        float4 v1 = lxyz[tid + (2 * j + 1) * 256];
        px[j] = (f32x2){v0.x, v1.x};
        py[j] = (f32x2){v0.y, v1.y};
        pz[j] = (f32x2){v0.z, v1.z};
        dist[j] = (f32x2){1e10f, 1e10f};
        lowc[2 * j] = ~(uint_t)(tid + (2 * j) * 256);
        lowc[2 * j + 1] = ~(uint_t)(tid + (2 * j + 1) * 256);
    }
    if (tid == 0) fpsidx[0] = 0;
    int cur = 0;
    const int lane = tid & 63, wid = tid >> 6;

    for (int it = 1; it < NPOINT; ++it) {
        float4 c = lxyz[cur];
        const f32x2 cx = (f32x2){c.x, c.x};
        const f32x2 cy = (f32x2){c.y, c.y};
        const f32x2 cz = (f32x2){c.z, c.z};
        u64 t[8];
#pragma unroll
        for (int j = 0; j < 8; j++) {
            f32x2 dx = px[j] - cx;
            f32x2 dy = py[j] - cy;
            f32x2 dz = pz[j] - cz;
            f32x2 d = (dx * dx + dy * dy) + dz * dz;   // contract OFF
            f32x2 nd = __builtin_elementwise_min(dist[j], d);
            dist[j] = nd;
            u64 e0 = ((u64)__float_as_uint(nd.x) << 32) | lowc[2 * j];
            u64 e1 = ((u64)__float_as_uint(nd.y) << 32) | lowc[2 * j + 1];
            t[j] = e0 > e1 ? e0 : e1;
        }
#pragma unroll
        for (int j = 0; j < 4; j++) { u64 o = t[j + 4]; t[j] = t[j] > o ? t[j] : o; }
        t[0] = t[0] > t[1] ? t[0] : t[1];
        t[2] = t[2] > t[3] ? t[2] : t[3];
        u64 v = t[0] > t[2] ? t[0] : t[2];

        uint_t lo = (uint_t)v, hi = (uint_t)(v >> 32);
        DPP_MAX_STAGE(0x111);   // row_shr:1
        DPP_MAX_STAGE(0x112);   // row_shr:2
        DPP_MAX_STAGE(0x114);   // row_shr:4
        DPP_MAX_STAGE(0x118);   // row_shr:8
        DPP_MAX_STAGE(0x142);   // row_bcast:15
        DPP_MAX_STAGE(0x143);   // row_bcast:31
        uint_t mlo = __builtin_amdgcn_readlane(lo, 63);
        uint_t mhi = __builtin_amdgcn_readlane(hi, 63);

        const int par = it & 1;
        if (lane == 0) wbest[par][wid] = ((u64)mhi << 32) | mlo;
        __syncthreads();
        u64 b0 = wbest[par][0], b1 = wbest[par][1];
        u64 b2 = wbest[par][2], b3 = wbest[par][3];
        u64 m01 = b0 > b1 ? b0 : b1;
        u64 m23 = b2 > b3 ? b2 : b3;
        u64 bb = m01 > m23 ? m01 : m23;
        cur = (int)(~(uint_t)bb) & (NPTS - 1);
        if (tid == 0) fpsidx[it] = cur;
        // parity buffering: next write to this slot is 2 barriers away -> safe
    }
    __syncthreads();
    float* ob = new_xyz + (size_t)b * NPOINT * 3;
    for (int s = tid; s < NPOINT; s += 256) {
        float4 v = lxyz[fpsidx[s]];
        ob[3 * s + 0] = v.x; ob[3 * s + 1] = v.y; ob[3 * s + 2] = v.z;
    }
}

// ---------------------------------------------------------------- ball query
__global__ __launch_bounds__(256) void ballq_kernel(const float* __restrict__ xyz,
                                                    const float* __restrict__ new_xyz,
                                                    int* __restrict__ gidx) {
    const int gw = (int)((blockIdx.x * 256 + threadIdx.x) >> 6);
    const int lane = threadIdx.x & 63;
    const int b = gw / NPOINT, s = gw % NPOINT;
    const float* nb = new_xyz + ((size_t)b * NPOINT + s) * 3;
    const float cx = nb[0], cy = nb[1], cz = nb[2];
    const float* xb = xyz + (size_t)b * NPTS * 3;
    const float r2 = (float)(0.2 * 0.2);
    int cnt = 0;
    int first = -1;
    int* out = gidx + (size_t)gw * NSAMPLE;
    for (int j0 = 0; j0 < NPTS; j0 += 64) {
        int j = j0 + lane;
        float dx = __fsub_rn(xb[j * 3 + 0], cx);
        float dy = __fsub_rn(xb[j * 3 + 1], cy);
        float dz = __fsub_rn(xb[j * 3 + 2], cz);
        float d = __fadd_rn(__fadd_rn(__fmul_rn(dx, dx), __fmul_rn(dy, dy)),
                            __fmul_rn(dz, dz));
        bool pred = !(d > r2);
        u64 mask = __ballot(pred);
        if (first < 0 && mask != 0ull) first = j0 + (__ffsll((long long)mask) - 1);
        int before = __popcll(mask & ((1ull << lane) - 1ull));
        int slot = cnt + before;
        if (pred && slot < NSAMPLE) out[slot] = j;
        cnt += (int)__popcll(mask);
        if (cnt >= NSAMPLE) break;
    }
    if (cnt < NSAMPLE) {
        if (lane >= cnt && lane < NSAMPLE) out[lane] = first;
    }
}

// ---------------------------------------------------------------- conv1 (MFMA, prepacked W, partial stats)
__global__ __launch_bounds__(256) void conv1_mfma(const float* __restrict__ xyz,
                                                  const float* __restrict__ points,
                                                  const float* __restrict__ new_xyz,
                                                  const int* __restrict__ gidx,
                                                  const ushort_t* __restrict__ Wp0,
                                                  const ushort_t* __restrict__ Wx0,
                                                  const float* __restrict__ bias,
                                                  ushort_t* __restrict__ Y,
                                                  float* __restrict__ part_s,
                                                  float* __restrict__ part_q) {
    const int lane = threadIdx.x & 63, wid = threadIdx.x >> 6;
    const int l15 = lane & 15, quad = lane >> 4;
    const int p0 = blockIdx.x * 128 + wid * 32;

    bf16x8 Bp[4], Bx[4];
#pragma unroll
    for (int nt = 0; nt < 4; nt++) {
        const int ch = nt * 16 + l15;
        Bp[nt] = *(const bf16x8*)(Wp0 + (size_t)ch * 32 + quad * 8);
        uint4 bx = {0u, 0u, 0u, 0u};
        if (quad == 0) {
            uint2 wv = *(const uint2*)(Wx0 + ch * 4);
            bx.x = wv.x; bx.y = wv.y;
        }
        Bx[nt] = asbf(bx);
    }
    f32x4 acc[2][4];
#pragma unroll
    for (int mt = 0; mt < 2; mt++)
#pragma unroll
        for (int nt = 0; nt < 4; nt++) acc[mt][nt] = (f32x4){0.f, 0.f, 0.f, 0.f};

#pragma unroll
    for (int mt = 0; mt < 2; mt++) {
        const int p = p0 + mt * 16 + l15;
        const int b = p >> 15, s = (p & 32767) >> 5;
        const int j = gidx[p];
        const float* pr = points + ((size_t)(b * NPTS + j)) * 32 + quad * 8;
        float4 pa = *(const float4*)pr;
        float4 pb4 = *(const float4*)(pr + 4);
        uint4 ap;
        ap.x = pkbf(pa.x, pa.y);  ap.y = pkbf(pa.z, pa.w);
        ap.z = pkbf(pb4.x, pb4.y); ap.w = pkbf(pb4.z, pb4.w);
        bf16x8 Ap = asbf(ap);
        uint4 ax = {0u, 0u, 0u, 0u};
        if (quad == 0) {
            const float* xp = xyz + ((size_t)(b * NPTS + j)) * 3;
            const float* nz = new_xyz + ((size_t)(b * NPOINT + s)) * 3;
            float d0 = xp[0] - nz[0], d1 = xp[1] - nz[1], d2 = xp[2] - nz[2];
            ax.x = pkbf(d0, d1);
            ax.y = pkbf(d2, 0.f);
        }
        bf16x8 Ax = asbf(ax);
#pragma unroll
        for (int nt = 0; nt < 4; nt++) {
            acc[mt][nt] = __builtin_amdgcn_mfma_f32_16x16x32_bf16(Ap, Bp[nt], acc[mt][nt], 0, 0, 0);
            acc[mt][nt] = __builtin_amdgcn_mfma_f32_16x16x32_bf16(Ax, Bx[nt], acc[mt][nt], 0, 0, 0);
        }
    }
    float s_[4], q_[4];
#pragma unroll
    for (int nt = 0; nt < 4; nt++) { s_[nt] = 0.f; q_[nt] = 0.f; }
#pragma unroll
    for (int nt = 0; nt < 4; nt++) {
        const int ch = nt * 16 + l15;
        const float bs = bias[ch];
#pragma unroll
        for (int mt = 0; mt < 2; mt++) {
            const int pb = p0 + mt * 16 + quad * 4;
            float x0 = acc[mt][nt][0] + bs, x1 = acc[mt][nt][1] + bs;
            float x2 = acc[mt][nt][2] + bs, x3 = acc[mt][nt][3] + bs;
            uint_t p01 = pkbf(x0, x1), p23 = pkbf(x2, x3);
            Y[(size_t)(pb + 0) * 64 + ch] = (ushort_t)(p01 & 0xffffu);
            Y[(size_t)(pb + 1) * 64 + ch] = (ushort_t)(p01 >> 16);
            Y[(size_t)(pb + 2) * 64 + ch] = (ushort_t)(p23 & 0xffffu);
            Y[(size_t)(pb + 3) * 64 + ch] = (ushort_t)(p23 >> 16);
            float v0 = __uint_as_float(p01 << 16), v1 = __uint_as_float(p01 & 0xffff0000u);
            float v2 = __uint_as_float(p23 << 16), v3 = __uint_as_float(p23 & 0xffff0000u);
            s_[nt] += (v0 + v1) + (v2 + v3);
            q_[nt] += (v0 * v0 + v1 * v1) + (v2 * v2 + v3 * v3);
        }
    }
#pragma unroll
    for (int nt = 0; nt < 4; nt++) {
        s_[nt] += __shfl_xor(s_[nt], 16, 64); s_[nt] += __shfl_xor(s_[nt], 32, 64);
        q_[nt] += __shfl_xor(q_[nt], 16, 64); q_[nt] += __shfl_xor(q_[nt], 32, 64);
    }
    __shared__ float reds[4][4][16], redq[4][4][16];
    if (lane < 16) {
#pragma unroll
        for (int nt = 0; nt < 4; nt++) { reds[wid][nt][lane] = s_[nt]; redq[wid][nt][lane] = q_[nt]; }
    }
    __syncthreads();
    if (threadIdx.x < 16) {
#pragma unroll
        for (int nt = 0; nt < 4; nt++) {
            float ss = 0.f, qq = 0.f;
#pragma unroll
            for (int w = 0; w < 4; w++) { ss += reds[w][nt][threadIdx.x]; qq += redq[w][nt][threadIdx.x]; }
            const int ch = nt * 16 + threadIdx.x;
            part_s[(size_t)ch * NBLK + blockIdx.x] = ss;
            part_q[(size_t)ch * NBLK + blockIdx.x] = qq;
        }
    }
}

// ---------------------------------------------------------------- convN (MFMA, prepacked W, BN+ReLU on load, partial stats)
template <int IN, int OUT>
__global__ __launch_bounds__(256) void convN_mfma(const ushort_t* __restrict__ Yin,
                                                  const float* __restrict__ scale,
                                                  const float* __restrict__ shift,
                                                  const ushort_t* __restrict__ Wp,
                                                  const float* __restrict__ bias,
                                                  ushort_t* __restrict__ Yout,
                                                  float* __restrict__ part_s,
                                                  float* __restrict__ part_q) {
    constexpr int NT = OUT / 16;
    const int lane = threadIdx.x & 63, wid = threadIdx.x >> 6;
    const int l15 = lane & 15, quad = lane >> 4;
    const int p0 = blockIdx.x * 128 + wid * 32;

    float sc[2][8], sh[2][8];
#pragma unroll
    for (int kq = 0; kq < 2; kq++) {
        const int i0 = kq * 32 + quad * 8;
        float4 a0 = *(const float4*)(scale + i0);
        float4 a1 = *(const float4*)(scale + i0 + 4);
        float4 b0v = *(const float4*)(shift + i0);
        float4 b1v = *(const float4*)(shift + i0 + 4);
        sc[kq][0] = a0.x; sc[kq][1] = a0.y; sc[kq][2] = a0.z; sc[kq][3] = a0.w;
        sc[kq][4] = a1.x; sc[kq][5] = a1.y; sc[kq][6] = a1.z; sc[kq][7] = a1.w;
        sh[kq][0] = b0v.x; sh[kq][1] = b0v.y; sh[kq][2] = b0v.z; sh[kq][3] = b0v.w;
        sh[kq][4] = b1v.x; sh[kq][5] = b1v.y; sh[kq][6] = b1v.z; sh[kq][7] = b1v.w;
    }
    bf16x8 Bf[NT][2];
#pragma unroll
    for (int nt = 0; nt < NT; nt++)
#pragma unroll
        for (int kq = 0; kq < 2; kq++)
            Bf[nt][kq] = *(const bf16x8*)(Wp + (size_t)(nt * 16 + l15) * IN + kq * 32 + quad * 8);

    bf16x8 Af[2][2];
#pragma unroll
    for (int mt = 0; mt < 2; mt++)
#pragma unroll
        for (int kq = 0; kq < 2; kq++) {
            const ushort_t* yr = Yin + (size_t)(p0 + mt * 16 + l15) * IN + kq * 32 + quad * 8;
            uint4 u = *(const uint4*)yr;
            float f[8]; unpack8(u, f);
            float g0 = fmaxf(fmaf(f[0], sc[kq][0], sh[kq][0]), 0.f);
            float g1 = fmaxf(fmaf(f[1], sc[kq][1], sh[kq][1]), 0.f);
            float g2 = fmaxf(fmaf(f[2], sc[kq][2], sh[kq][2]), 0.f);
            float g3 = fmaxf(fmaf(f[3], sc[kq][3], sh[kq][3]), 0.f);
            float g4 = fmaxf(fmaf(f[4], sc[kq][4], sh[kq][4]), 0.f);
            float g5 = fmaxf(fmaf(f[5], sc[kq][5], sh[kq][5]), 0.f);
            float g6 = fmaxf(fmaf(f[6], sc[kq][6], sh[kq][6]), 0.f);
            float g7 = fmaxf(fmaf(f[7], sc[kq][7], sh[kq][7]), 0.f);
            uint4 a;
            a.x = pkbf(g0, g1); a.y = pkbf(g2, g3);
            a.z = pkbf(g4, g5); a.w = pkbf(g6, g7);
            Af[mt][kq] = asbf(a);
        }

    f32x4 acc[2][NT];
#pragma unroll
    for (int mt = 0; mt < 2; mt++)
#pragma unroll
        for (int nt = 0; nt < NT; nt++) acc[mt][nt] = (f32x4){0.f, 0.f, 0.f, 0.f};
#pragma unroll
    for (int mt = 0; mt < 2; mt++)
#pragma unroll
        for (int nt = 0; nt < NT; nt++) {
            acc[mt][nt] = __builtin_amdgcn_mfma_f32_16x16x32_bf16(Af[mt][0], Bf[nt][0], acc[mt][nt], 0, 0, 0);
            acc[mt][nt] = __builtin_amdgcn_mfma_f32_16x16x32_bf16(Af[mt][1], Bf[nt][1], acc[mt][nt], 0, 0, 0);
        }
    float s_[NT], q_[NT];
#pragma unroll
    for (int nt = 0; nt < NT; nt++) { s_[nt] = 0.f; q_[nt] = 0.f; }
#pragma unroll
    for (int nt = 0; nt < NT; nt++) {
        const int ch = nt * 16 + l15;
        const float bs = bias[ch];
#pragma unroll
        for (int mt = 0; mt < 2; mt++) {
            const int pb = p0 + mt * 16 + quad * 4;
            float x0 = acc[mt][nt][0] + bs, x1 = acc[mt][nt][1] + bs;
            float x2 = acc[mt][nt][2] + bs, x3 = acc[mt][nt][3] + bs;
            uint_t p01 = pkbf(x0, x1), p23 = pkbf(x2, x3);
            Yout[(size_t)(pb + 0) * OUT + ch] = (ushort_t)(p01 & 0xffffu);
            Yout[(size_t)(pb + 1) * OUT + ch] = (ushort_t)(p01 >> 16);
            Yout[(size_t)(pb + 2) * OUT + ch] = (ushort_t)(p23 & 0xffffu);
            Yout[(size_t)(pb + 3) * OUT + ch] = (ushort_t)(p23 >> 16);
            float v0 = __uint_as_float(p01 << 16), v1 = __uint_as_float(p01 & 0xffff0000u);
            float v2 = __uint_as_float(p23 << 16), v3 = __uint_as_float(p23 & 0xffff0000u);
            s_[nt] += (v0 + v1) + (v2 + v3);
            q_[nt] += (v0 * v0 + v1 * v1) + (v2 * v2 + v3 * v3);
        }
    }
#pragma unroll
    for (int nt = 0; nt < NT; nt++) {
        s_[nt] += __shfl_xor(s_[nt], 16, 64); s_[nt] += __shfl_xor(s_[nt], 32, 64);
        q_[nt] += __shfl_xor(q_[nt], 16, 64); q_[nt] += __shfl_xor(q_[nt], 32, 64);
    }
    __shared__ float reds[4][NT][16], redq[4][NT][16];
    if (lane < 16) {
#pragma unroll
        for (int nt = 0; nt < NT; nt++) { reds[wid][nt][lane] = s_[nt]; redq[wid][nt][lane] = q_[nt]; }
    }
    __syncthreads();
    if (threadIdx.x < 16) {
#pragma unroll
        for (int nt = 0; nt < NT; nt++) {
            float ss = 0.f, qq = 0.f;
#pragma unroll
            for (int w = 0; w < 4; w++) { ss += reds[w][nt][threadIdx.x]; qq += redq[w][nt][threadIdx.x]; }
            const int ch = nt * 16 + threadIdx.x;
            part_s[(size_t)ch * NBLK + blockIdx.x] = ss;
            part_q[(size_t)ch * NBLK + blockIdx.x] = qq;
        }
    }
}

// ---------------------------------------------------------------- reduce partials -> BN scale/shift
__global__ __launch_bounds__(256) void reduce_finalize(const float* __restrict__ part_s,
                                                       const float* __restrict__ part_q,
                                                       const float* __restrict__ g,
                                                       const float* __restrict__ be,
                                                       float* __restrict__ scale,
                                                       float* __restrict__ shift) {
    const int ch = blockIdx.x;
    const float* p1 = part_s + (size_t)ch * NBLK;
    const float* p2 = part_q + (size_t)ch * NBLK;
    float s = 0.f, q = 0.f;
    for (int i = threadIdx.x; i < NBLK; i += 256) { s += p1[i]; q += p2[i]; }
#pragma unroll
    for (int m = 1; m < 64; m <<= 1) { s += __shfl_xor(s, m, 64); q += __shfl_xor(q, m, 64); }
    __shared__ float ls[4], lq[4];
    const int lane = threadIdx.x & 63, wid = threadIdx.x >> 6;
    if (lane == 0) { ls[wid] = s; lq[wid] = q; }
    __syncthreads();
    if (threadIdx.x == 0) {
        float ssum = ls[0] + ls[1] + ls[2] + ls[3];
        float qsum = lq[0] + lq[1] + lq[2] + lq[3];
        float mean = ssum * (1.f / (float)NPOS);
        float var = qsum * (1.f / (float)NPOS) - mean * mean;
        float inv = 1.f / sqrtf(var + EPSV);
        float sc = g[ch] * inv;
        scale[ch] = sc;
        shift[ch] = be[ch] - mean * sc;
    }
}

// ---------------------------------------------------------------- BN3 + ReLU + max over k
__global__ __launch_bounds__(256) void final_kernel(const ushort_t* __restrict__ Y3,
                                                    const float* __restrict__ scale,
                                                    const float* __restrict__ shift,
                                                    float* __restrict__ out) {
    const int b = blockIdx.x >> 5;
    const int stile = (blockIdx.x & 31) * 32;
    const int sl = threadIdx.x >> 3;
    const int oc = threadIdx.x & 7;
    const int s = stile + sl;
    const size_t base = ((size_t)(b * NPOINT + s)) * 32 * 128 + oc * 16;
    float vmax[16];
#pragma unroll
    for (int i = 0; i < 16; i++) vmax[i] = 0.f;
    for (int k = 0; k < 32; k++) {
        const ushort_t* yp = Y3 + base + (size_t)k * 128;
#pragma unroll
        for (int h = 0; h < 2; h++) {
            uint4 u = *(const uint4*)(yp + h * 8);
            float f[8];
            unpack8(u, f);
#pragma unroll
            for (int i = 0; i < 8; i++) {
                int o = oc * 16 + h * 8 + i;
                float v = fmaf(f[i], scale[o], shift[o]);
                vmax[h * 8 + i] = fmaxf(vmax[h * 8 + i], v);
            }
        }
    }
    __shared__ float res[32][130];
#pragma unroll
    for (int i = 0; i < 16; i++) res[sl][oc * 16 + i] = vmax[i];
    __syncthreads();
    const int so = threadIdx.x & 31;
    const int og = threadIdx.x >> 5;
#pragma unroll
    for (int r = 0; r < 16; r++) {
        int o = og * 16 + r;
        out[((size_t)(b * 128 + o)) * NPOINT + stile + so] = res[so][o];
    }
}

// ---------------------------------------------------------------- launch
extern "C" void kernel_launch(void* const* d_in, const int* in_sizes, int n_in,
                              void* d_out, int out_size, void* d_ws, size_t ws_size,
                              hipStream_t stream) {
    const float* xyz = (const float*)d_in[0];
    const float* points = (const float*)d_in[1];
    const float* w0 = (const float*)d_in[2];
    const float* b0 = (const float*)d_in[3];
    const float* g0 = (const float*)d_in[4];
    const float* be0 = (const float*)d_in[5];
    const float* w1 = (const float*)d_in[6];
    const float* b1 = (const float*)d_in[7];
    const float* g1 = (const float*)d_in[8];
    const float* be1 = (const float*)d_in[9];
    const float* w2 = (const float*)d_in[10];
    const float* b2 = (const float*)d_in[11];
    const float* g2 = (const float*)d_in[12];
    const float* be2 = (const float*)d_in[13];

    float* out = (float*)d_out;
    float* new_xyz = out;                      // B*NPOINT*3 = 49152
    float* final_out = out + BATCH * NPOINT * 3;

    // workspace layout (~202 MiB; Y3 overlays Y1 -- Y1 dead after conv2)
    char* ws = (char*)d_ws;
    const size_t MB = 1024u * 1024u;
    const size_t o_gidx = 0;
    const size_t o_y2 = 2 * MB;
    const size_t o_y13 = o_y2 + (size_t)NPOS * 64 * 2;
    const size_t o_params = o_y13 + (size_t)NPOS * 128 * 2;   // 512 floats
    const size_t o_parts = o_params + 4096;                   // 2 x 128*4096 floats = 4 MiB
    const size_t o_w = o_parts + 4 * MB;                      // packed bf16 weights (~32 KiB)

    int* gidx = (int*)(ws + o_gidx);
    ushort_t* Y1 = (ushort_t*)(ws + o_y13);
    ushort_t* Y2 = (ushort_t*)(ws + o_y2);
    ushort_t* Y3 = (ushort_t*)(ws + o_y13);
    float* pr = (float*)(ws + o_params);
    float* scale1 = pr + 0, *shift1 = pr + 64;
    float* scale2 = pr + 128, *shift2 = pr + 192;
    float* scale3 = pr + 256, *shift3 = pr + 384;
    float* part_s = (float*)(ws + o_parts);
    float* part_q = part_s + (size_t)128 * NBLK;
    ushort_t* Wp0 = (ushort_t*)(ws + o_w);            // 64*32
    ushort_t* Wx0 = Wp0 + 64 * 32;                    // 64*4
    ushort_t* Wp1 = Wx0 + 64 * 4;                     // 64*64
    ushort_t* Wp2 = Wp1 + 64 * 64;                    // 128*64

    prep_w<<<8, 256, 0, stream>>>(w0, w1, w2, Wp0, Wx0, Wp1, Wp2);
    fps_kernel<<<BATCH, 256, 0, stream>>>(xyz, new_xyz);
    ballq_kernel<<<(BATCH * NPOINT) / 4, 256, 0, stream>>>(xyz, new_xyz, gidx);
    conv1_mfma<<<NBLK, 256, 0, stream>>>(xyz, points, new_xyz, gidx, Wp0, Wx0, b0, Y1, part_s, part_q);
    reduce_finalize<<<64, 256, 0, stream>>>(part_s, part_q, g0, be0, scale1, shift1);
    convN_mfma<64, 64><<<NBLK, 256, 0, stream>>>(Y1, scale1, shift1, Wp1, b1, Y2, part_s, part_q);
    reduce_finalize<<<64, 256, 0, stream>>>(part_s, part_q, g1, be1, scale2, shift2);
    convN_mfma<64, 128><<<NBLK, 256, 0, stream>>>(Y2, scale2, shift2, Wp2, b2, Y3, part_s, part_q);
    reduce_finalize<<<128, 256, 0, stream>>>(part_s, part_q, g2, be2, scale3, shift3);
    final_kernel<<<BATCH * 32, 256, 0, stream>>>(Y3, scale3, shift3, final_out);
}

// Round 9
// 890.861 us; speedup vs baseline: 1.2491x; 1.0210x over previous
//
#include <hip/hip_runtime.h>
#include <hip/hip_bf16.h>
#include <stdint.h>

#pragma clang fp contract(off)

#define BATCH   16
#define NPTS    4096
#define NPOINT  1024
#define NSAMPLE 32
#define NPOS    (BATCH*NPOINT*NSAMPLE)   // 524288
#define NBLK    (NPOS/128)               // 4096 conv blocks
#define NGRP    (BATCH*NPOINT)           // 16384 s-groups
#define EPSV    1e-5f

typedef unsigned short ushort_t;
typedef unsigned int uint_t;
typedef unsigned long long u64;
typedef __attribute__((ext_vector_type(8))) short bf16x8;
typedef __attribute__((ext_vector_type(4))) float f32x4;
typedef __attribute__((ext_vector_type(2))) float f32x2;

__device__ inline ushort_t f2bf(float f) {
    uint_t u = __float_as_uint(f);
    u += 0x7fffu + ((u >> 16) & 1u);   // RNE
    return (ushort_t)(u >> 16);
}
__device__ inline uint_t pkbf(float a, float b) {
    __hip_bfloat162 h = __float22bfloat162_rn(make_float2(a, b));
    uint_t r; __builtin_memcpy(&r, &h, 4); return r;
}
__device__ inline bf16x8 asbf(uint4 u) {
    bf16x8 v; __builtin_memcpy(&v, &u, 16); return v;
}
__device__ inline void unpack8(uint4 u, float* f) {
    f[0] = __uint_as_float(u.x << 16); f[1] = __uint_as_float(u.x & 0xffff0000u);
    f[2] = __uint_as_float(u.y << 16); f[3] = __uint_as_float(u.y & 0xffff0000u);
    f[4] = __uint_as_float(u.z << 16); f[5] = __uint_as_float(u.z & 0xffff0000u);
    f[6] = __uint_as_float(u.w << 16); f[7] = __uint_as_float(u.w & 0xffff0000u);
}

// ---------------------------------------------------------------- weight prep (fp32 -> bf16, frag order)
__global__ __launch_bounds__(256) void prep_w(const float* __restrict__ w0,
                                              const float* __restrict__ w1,
                                              const float* __restrict__ w2,
                                              ushort_t* __restrict__ Wp0,
                                              ushort_t* __restrict__ Wx0,
                                              ushort_t* __restrict__ Wp1,
                                              ushort_t* __restrict__ Wp2) {
    const int t = blockIdx.x * 256 + threadIdx.x;
    const int stride = gridDim.x * 256;
    for (int i = t; i < 64 * 32; i += stride) { int ch = i >> 5, k = i & 31; Wp0[i] = f2bf(w0[ch * 35 + 3 + k]); }
    for (int i = t; i < 64 * 4;  i += stride) { int ch = i >> 2, q = i & 3;  Wx0[i] = (q < 3) ? f2bf(w0[ch * 35 + q]) : (ushort_t)0; }
    for (int i = t; i < 64 * 64; i += stride) Wp1[i] = f2bf(w1[i]);
    for (int i = t; i < 128 * 64; i += stride) Wp2[i] = f2bf(w2[i]);
}

// ---------------------------------------------------------------- FPS (R5/R7 256-thread version)
#define DPP_MAX_STAGE(CTRL) do {                                              \
    uint_t _lo2 = __builtin_amdgcn_update_dpp(lo, lo, CTRL, 0xf, 0xf, false); \
    uint_t _hi2 = __builtin_amdgcn_update_dpp(hi, hi, CTRL, 0xf, 0xf, false); \
    u64 _o = ((u64)_hi2 << 32) | _lo2;                                        \
    u64 _v = ((u64)hi << 32) | lo;                                            \
    bool _g = _o > _v;                                                        \
    lo = _g ? _lo2 : lo; hi = _g ? _hi2 : hi;                                 \
} while (0)

__global__ __launch_bounds__(256) void fps_kernel(const float* __restrict__ xyz,
                                                  float* __restrict__ new_xyz) {
    __shared__ float4 lxyz[NPTS];     // 64 KiB
    __shared__ u64 wbest[2][4];
    __shared__ int fpsidx[NPOINT];
    const int b = blockIdx.x;
    const int tid = threadIdx.x;
    const float* base = xyz + (size_t)b * NPTS * 3;
    for (int n = tid; n < NPTS; n += 256) {
        lxyz[n] = make_float4(base[3 * n], base[3 * n + 1], base[3 * n + 2], 0.f);
    }
    __syncthreads();

    f32x2 px[8], py[8], pz[8], dist[8];
    uint_t lowc[16];   // ~idx, iteration-invariant (smaller idx wins ties)
#pragma unroll
    for (int j = 0; j < 8; j++) {
        float4 v0 = lxyz[tid + (2 * j) * 256];
        float4 v1 = lxyz[tid + (2 * j + 1) * 256];
        px[j] = (f32x2){v0.x, v1.x};
        py[j] = (f32x2){v0.y, v1.y};
        pz[j] = (f32x2){v0.z, v1.z};
        dist[j] = (f32x2){1e10f, 1e10f};
        lowc[2 * j] = ~(uint_t)(tid + (2 * j) * 256);
        lowc[2 * j + 1] = ~(uint_t)(tid + (2 * j + 1) * 256);
    }
    if (tid == 0) fpsidx[0] = 0;
    int cur = 0;
    const int lane = tid & 63, wid = tid >> 6;

    for (int it = 1; it < NPOINT; ++it) {
        float4 c = lxyz[cur];
        const f32x2 cx = (f32x2){c.x, c.x};
        const f32x2 cy = (f32x2){c.y, c.y};
        const f32x2 cz = (f32x2){c.z, c.z};
        u64 t[8];
#pragma unroll
        for (int j = 0; j < 8; j++) {
            f32x2 dx = px[j] - cx;
            f32x2 dy = py[j] - cy;
            f32x2 dz = pz[j] - cz;
            f32x2 d = (dx * dx + dy * dy) + dz * dz;   // contract OFF
            f32x2 nd = __builtin_elementwise_min(dist[j], d);
            dist[j] = nd;
            u64 e0 = ((u64)__float_as_uint(nd.x) << 32) | lowc[2 * j];
            u64 e1 = ((u64)__float_as_uint(nd.y) << 32) | lowc[2 * j + 1];
            t[j] = e0 > e1 ? e0 : e1;
        }
#pragma unroll
        for (int j = 0; j < 4; j++) { u64 o = t[j + 4]; t[j] = t[j] > o ? t[j] : o; }
        t[0] = t[0] > t[1] ? t[0] : t[1];
        t[2] = t[2] > t[3] ? t[2] : t[3];
        u64 v = t[0] > t[2] ? t[0] : t[2];

        uint_t lo = (uint_t)v, hi = (uint_t)(v >> 32);
        DPP_MAX_STAGE(0x111);   // row_shr:1
        DPP_MAX_STAGE(0x112);   // row_shr:2
        DPP_MAX_STAGE(0x114);   // row_shr:4
        DPP_MAX_STAGE(0x118);   // row_shr:8
        DPP_MAX_STAGE(0x142);   // row_bcast:15
        DPP_MAX_STAGE(0x143);   // row_bcast:31
        uint_t mlo = __builtin_amdgcn_readlane(lo, 63);
        uint_t mhi = __builtin_amdgcn_readlane(hi, 63);

        const int par = it & 1;
        if (lane == 0) wbest[par][wid] = ((u64)mhi << 32) | mlo;
        __syncthreads();
        u64 b0 = wbest[par][0], b1 = wbest[par][1];
        u64 b2 = wbest[par][2], b3 = wbest[par][3];
        u64 m01 = b0 > b1 ? b0 : b1;
        u64 m23 = b2 > b3 ? b2 : b3;
        u64 bb = m01 > m23 ? m01 : m23;
        cur = (int)(~(uint_t)bb) & (NPTS - 1);
        if (tid == 0) fpsidx[it] = cur;
        // parity buffering: next write to this slot is 2 barriers away -> safe
    }
    __syncthreads();
    float* ob = new_xyz + (size_t)b * NPOINT * 3;
    for (int s = tid; s < NPOINT; s += 256) {
        float4 v = lxyz[fpsidx[s]];
        ob[3 * s + 0] = v.x; ob[3 * s + 1] = v.y; ob[3 * s + 2] = v.z;
    }
}

// ---------------------------------------------------------------- ball query
__global__ __launch_bounds__(256) void ballq_kernel(const float* __restrict__ xyz,
                                                    const float* __restrict__ new_xyz,
                                                    int* __restrict__ gidx) {
    const int gw = (int)((blockIdx.x * 256 + threadIdx.x) >> 6);
    const int lane = threadIdx.x & 63;
    const int b = gw / NPOINT, s = gw % NPOINT;
    const float* nb = new_xyz + ((size_t)b * NPOINT + s) * 3;
    const float cx = nb[0], cy = nb[1], cz = nb[2];
    const float* xb = xyz + (size_t)b * NPTS * 3;
    const float r2 = (float)(0.2 * 0.2);
    int cnt = 0;
    int first = -1;
    int* out = gidx + (size_t)gw * NSAMPLE;
    for (int j0 = 0; j0 < NPTS; j0 += 64) {
        int j = j0 + lane;
        float dx = __fsub_rn(xb[j * 3 + 0], cx);
        float dy = __fsub_rn(xb[j * 3 + 1], cy);
        float dz = __fsub_rn(xb[j * 3 + 2], cz);
        float d = __fadd_rn(__fadd_rn(__fmul_rn(dx, dx), __fmul_rn(dy, dy)),
                            __fmul_rn(dz, dz));
        bool pred = !(d > r2);
        u64 mask = __ballot(pred);
        if (first < 0 && mask != 0ull) first = j0 + (__ffsll((long long)mask) - 1);
        int before = __popcll(mask & ((1ull << lane) - 1ull));
        int slot = cnt + before;
        if (pred && slot < NSAMPLE) out[slot] = j;
        cnt += (int)__popcll(mask);
        if (cnt >= NSAMPLE) break;
    }
    if (cnt < NSAMPLE) {
        if (lane >= cnt && lane < NSAMPLE) out[lane] = first;
    }
}

// ---------------------------------------------------------------- conv1 (MFMA, prepacked W, partial stats)
__global__ __launch_bounds__(256) void conv1_mfma(const float* __restrict__ xyz,
                                                  const float* __restrict__ points,
                                                  const float* __restrict__ new_xyz,
                                                  const int* __restrict__ gidx,
                                                  const ushort_t* __restrict__ Wp0,
                                                  const ushort_t* __restrict__ Wx0,
                                                  const float* __restrict__ bias,
                                                  ushort_t* __restrict__ Y,
                                                  float* __restrict__ part_s,
                                                  float* __restrict__ part_q) {
    const int lane = threadIdx.x & 63, wid = threadIdx.x >> 6;
    const int l15 = lane & 15, quad = lane >> 4;
    const int p0 = blockIdx.x * 128 + wid * 32;

    bf16x8 Bp[4], Bx[4];
#pragma unroll
    for (int nt = 0; nt < 4; nt++) {
        const int ch = nt * 16 + l15;
        Bp[nt] = *(const bf16x8*)(Wp0 + (size_t)ch * 32 + quad * 8);
        uint4 bx = {0u, 0u, 0u, 0u};
        if (quad == 0) {
            uint2 wv = *(const uint2*)(Wx0 + ch * 4);
            bx.x = wv.x; bx.y = wv.y;
        }
        Bx[nt] = asbf(bx);
    }
    f32x4 acc[2][4];
#pragma unroll
    for (int mt = 0; mt < 2; mt++)
#pragma unroll
        for (int nt = 0; nt < 4; nt++) acc[mt][nt] = (f32x4){0.f, 0.f, 0.f, 0.f};

#pragma unroll
    for (int mt = 0; mt < 2; mt++) {
        const int p = p0 + mt * 16 + l15;
        const int b = p >> 15, s = (p & 32767) >> 5;
        const int j = gidx[p];
        const float* pr = points + ((size_t)(b * NPTS + j)) * 32 + quad * 8;
        float4 pa = *(const float4*)pr;
        float4 pb4 = *(const float4*)(pr + 4);
        uint4 ap;
        ap.x = pkbf(pa.x, pa.y);  ap.y = pkbf(pa.z, pa.w);
        ap.z = pkbf(pb4.x, pb4.y); ap.w = pkbf(pb4.z, pb4.w);
        bf16x8 Ap = asbf(ap);
        uint4 ax = {0u, 0u, 0u, 0u};
        if (quad == 0) {
            const float* xp = xyz + ((size_t)(b * NPTS + j)) * 3;
            const float* nz = new_xyz + ((size_t)(b * NPOINT + s)) * 3;
            float d0 = xp[0] - nz[0], d1 = xp[1] - nz[1], d2 = xp[2] - nz[2];
            ax.x = pkbf(d0, d1);
            ax.y = pkbf(d2, 0.f);
        }
        bf16x8 Ax = asbf(ax);
#pragma unroll
        for (int nt = 0; nt < 4; nt++) {
            acc[mt][nt] = __builtin_amdgcn_mfma_f32_16x16x32_bf16(Ap, Bp[nt], acc[mt][nt], 0, 0, 0);
            acc[mt][nt] = __builtin_amdgcn_mfma_f32_16x16x32_bf16(Ax, Bx[nt], acc[mt][nt], 0, 0, 0);
        }
    }
    float s_[4], q_[4];
#pragma unroll
    for (int nt = 0; nt < 4; nt++) { s_[nt] = 0.f; q_[nt] = 0.f; }
#pragma unroll
    for (int nt = 0; nt < 4; nt++) {
        const int ch = nt * 16 + l15;
        const float bs = bias[ch];
#pragma unroll
        for (int mt = 0; mt < 2; mt++) {
            const int pb = p0 + mt * 16 + quad * 4;
            float x0 = acc[mt][nt][0] + bs, x1 = acc[mt][nt][1] + bs;
            float x2 = acc[mt][nt][2] + bs, x3 = acc[mt][nt][3] + bs;
            uint_t p01 = pkbf(x0, x1), p23 = pkbf(x2, x3);
            Y[(size_t)(pb + 0) * 64 + ch] = (ushort_t)(p01 & 0xffffu);
            Y[(size_t)(pb + 1) * 64 + ch] = (ushort_t)(p01 >> 16);
            Y[(size_t)(pb + 2) * 64 + ch] = (ushort_t)(p23 & 0xffffu);
            Y[(size_t)(pb + 3) * 64 + ch] = (ushort_t)(p23 >> 16);
            float v0 = __uint_as_float(p01 << 16), v1 = __uint_as_float(p01 & 0xffff0000u);
            float v2 = __uint_as_float(p23 << 16), v3 = __uint_as_float(p23 & 0xffff0000u);
            s_[nt] += (v0 + v1) + (v2 + v3);
            q_[nt] += (v0 * v0 + v1 * v1) + (v2 * v2 + v3 * v3);
        }
    }
#pragma unroll
    for (int nt = 0; nt < 4; nt++) {
        s_[nt] += __shfl_xor(s_[nt], 16, 64); s_[nt] += __shfl_xor(s_[nt], 32, 64);
        q_[nt] += __shfl_xor(q_[nt], 16, 64); q_[nt] += __shfl_xor(q_[nt], 32, 64);
    }
    __shared__ float reds[4][4][16], redq[4][4][16];
    if (lane < 16) {
#pragma unroll
        for (int nt = 0; nt < 4; nt++) { reds[wid][nt][lane] = s_[nt]; redq[wid][nt][lane] = q_[nt]; }
    }
    __syncthreads();
    if (threadIdx.x < 16) {
#pragma unroll
        for (int nt = 0; nt < 4; nt++) {
            float ss = 0.f, qq = 0.f;
#pragma unroll
            for (int w = 0; w < 4; w++) { ss += reds[w][nt][threadIdx.x]; qq += redq[w][nt][threadIdx.x]; }
            const int ch = nt * 16 + threadIdx.x;
            part_s[(size_t)ch * NBLK + blockIdx.x] = ss;
            part_q[(size_t)ch * NBLK + blockIdx.x] = qq;
        }
    }
}

// ---------------------------------------------------------------- conv2 (MFMA, BN+ReLU on load, partial stats)
__global__ __launch_bounds__(256) void conv2_mfma(const ushort_t* __restrict__ Yin,
                                                  const float* __restrict__ scale,
                                                  const float* __restrict__ shift,
                                                  const ushort_t* __restrict__ Wp,
                                                  const float* __restrict__ bias,
                                                  ushort_t* __restrict__ Yout,
                                                  float* __restrict__ part_s,
                                                  float* __restrict__ part_q) {
    constexpr int IN = 64, OUT = 64, NT = 4;
    const int lane = threadIdx.x & 63, wid = threadIdx.x >> 6;
    const int l15 = lane & 15, quad = lane >> 4;
    const int p0 = blockIdx.x * 128 + wid * 32;

    float sc[2][8], sh[2][8];
#pragma unroll
    for (int kq = 0; kq < 2; kq++) {
        const int i0 = kq * 32 + quad * 8;
#pragma unroll
        for (int q = 0; q < 8; q++) { sc[kq][q] = scale[i0 + q]; sh[kq][q] = shift[i0 + q]; }
    }
    bf16x8 Bf[NT][2];
#pragma unroll
    for (int nt = 0; nt < NT; nt++)
#pragma unroll
        for (int kq = 0; kq < 2; kq++)
            Bf[nt][kq] = *(const bf16x8*)(Wp + (size_t)(nt * 16 + l15) * IN + kq * 32 + quad * 8);

    bf16x8 Af[2][2];
#pragma unroll
    for (int mt = 0; mt < 2; mt++)
#pragma unroll
        for (int kq = 0; kq < 2; kq++) {
            const ushort_t* yr = Yin + (size_t)(p0 + mt * 16 + l15) * IN + kq * 32 + quad * 8;
            uint4 u = *(const uint4*)yr;
            float f[8]; unpack8(u, f);
            float g0 = fmaxf(fmaf(f[0], sc[kq][0], sh[kq][0]), 0.f);
            float g1 = fmaxf(fmaf(f[1], sc[kq][1], sh[kq][1]), 0.f);
            float g2 = fmaxf(fmaf(f[2], sc[kq][2], sh[kq][2]), 0.f);
            float g3 = fmaxf(fmaf(f[3], sc[kq][3], sh[kq][3]), 0.f);
            float g4 = fmaxf(fmaf(f[4], sc[kq][4], sh[kq][4]), 0.f);
            float g5 = fmaxf(fmaf(f[5], sc[kq][5], sh[kq][5]), 0.f);
            float g6 = fmaxf(fmaf(f[6], sc[kq][6], sh[kq][6]), 0.f);
            float g7 = fmaxf(fmaf(f[7], sc[kq][7], sh[kq][7]), 0.f);
            uint4 a;
            a.x = pkbf(g0, g1); a.y = pkbf(g2, g3);
            a.z = pkbf(g4, g5); a.w = pkbf(g6, g7);
            Af[mt][kq] = asbf(a);
        }

    f32x4 acc[2][NT];
#pragma unroll
    for (int mt = 0; mt < 2; mt++)
#pragma unroll
        for (int nt = 0; nt < NT; nt++) acc[mt][nt] = (f32x4){0.f, 0.f, 0.f, 0.f};
#pragma unroll
    for (int mt = 0; mt < 2; mt++)
#pragma unroll
        for (int nt = 0; nt < NT; nt++) {
            acc[mt][nt] = __builtin_amdgcn_mfma_f32_16x16x32_bf16(Af[mt][0], Bf[nt][0], acc[mt][nt], 0, 0, 0);
            acc[mt][nt] = __builtin_amdgcn_mfma_f32_16x16x32_bf16(Af[mt][1], Bf[nt][1], acc[mt][nt], 0, 0, 0);
        }
    float s_[NT], q_[NT];
#pragma unroll
    for (int nt = 0; nt < NT; nt++) { s_[nt] = 0.f; q_[nt] = 0.f; }
#pragma unroll
    for (int nt = 0; nt < NT; nt++) {
        const int ch = nt * 16 + l15;
        const float bs = bias[ch];
#pragma unroll
        for (int mt = 0; mt < 2; mt++) {
            const int pb = p0 + mt * 16 + quad * 4;
            float x0 = acc[mt][nt][0] + bs, x1 = acc[mt][nt][1] + bs;
            float x2 = acc[mt][nt][2] + bs, x3 = acc[mt][nt][3] + bs;
            uint_t p01 = pkbf(x0, x1), p23 = pkbf(x2, x3);
            Yout[(size_t)(pb + 0) * OUT + ch] = (ushort_t)(p01 & 0xffffu);
            Yout[(size_t)(pb + 1) * OUT + ch] = (ushort_t)(p01 >> 16);
            Yout[(size_t)(pb + 2) * OUT + ch] = (ushort_t)(p23 & 0xffffu);
            Yout[(size_t)(pb + 3) * OUT + ch] = (ushort_t)(p23 >> 16);
            float v0 = __uint_as_float(p01 << 16), v1 = __uint_as_float(p01 & 0xffff0000u);
            float v2 = __uint_as_float(p23 << 16), v3 = __uint_as_float(p23 & 0xffff0000u);
            s_[nt] += (v0 + v1) + (v2 + v3);
            q_[nt] += (v0 * v0 + v1 * v1) + (v2 * v2 + v3 * v3);
        }
    }
#pragma unroll
    for (int nt = 0; nt < NT; nt++) {
        s_[nt] += __shfl_xor(s_[nt], 16, 64); s_[nt] += __shfl_xor(s_[nt], 32, 64);
        q_[nt] += __shfl_xor(q_[nt], 16, 64); q_[nt] += __shfl_xor(q_[nt], 32, 64);
    }
    __shared__ float reds[4][NT][16], redq[4][NT][16];
    if (lane < 16) {
#pragma unroll
        for (int nt = 0; nt < NT; nt++) { reds[wid][nt][lane] = s_[nt]; redq[wid][nt][lane] = q_[nt]; }
    }
    __syncthreads();
    if (threadIdx.x < 16) {
#pragma unroll
        for (int nt = 0; nt < NT; nt++) {
            float ss = 0.f, qq = 0.f;
#pragma unroll
            for (int w = 0; w < 4; w++) { ss += reds[w][nt][threadIdx.x]; qq += redq[w][nt][threadIdx.x]; }
            const int ch = nt * 16 + threadIdx.x;
            part_s[(size_t)ch * NBLK + blockIdx.x] = ss;
            part_q[(size_t)ch * NBLK + blockIdx.x] = qq;
        }
    }
}

// ---------------------------------------------------------------- conv3 (MFMA; NO Y3 -- emits per-group max/min of fp32 pre-BN x)
// Each wave's 32 positions are exactly one s-group (p0 multiple of 32).
__global__ __launch_bounds__(256) void conv3_mfma(const ushort_t* __restrict__ Yin,
                                                  const float* __restrict__ scale,
                                                  const float* __restrict__ shift,
                                                  const ushort_t* __restrict__ Wp,
                                                  const float* __restrict__ bias,
                                                  float* __restrict__ xmax,
                                                  float* __restrict__ xmin,
                                                  float* __restrict__ part_s,
                                                  float* __restrict__ part_q) {
    constexpr int IN = 64, NT = 8;
    const int lane = threadIdx.x & 63, wid = threadIdx.x >> 6;
    const int l15 = lane & 15, quad = lane >> 4;
    const int p0 = blockIdx.x * 128 + wid * 32;
    const int g = p0 >> 5;   // s-group of this wave

    float sc[2][8], sh[2][8];
#pragma unroll
    for (int kq = 0; kq < 2; kq++) {
        const int i0 = kq * 32 + quad * 8;
#pragma unroll
        for (int q = 0; q < 8; q++) { sc[kq][q] = scale[i0 + q]; sh[kq][q] = shift[i0 + q]; }
    }
    bf16x8 Bf[NT][2];
#pragma unroll
    for (int nt = 0; nt < NT; nt++)
#pragma unroll
        for (int kq = 0; kq < 2; kq++)
            Bf[nt][kq] = *(const bf16x8*)(Wp + (size_t)(nt * 16 + l15) * IN + kq * 32 + quad * 8);

    bf16x8 Af[2][2];
#pragma unroll
    for (int mt = 0; mt < 2; mt++)
#pragma unroll
        for (int kq = 0; kq < 2; kq++) {
            const ushort_t* yr = Yin + (size_t)(p0 + mt * 16 + l15) * IN + kq * 32 + quad * 8;
            uint4 u = *(const uint4*)yr;
            float f[8]; unpack8(u, f);
            float g0 = fmaxf(fmaf(f[0], sc[kq][0], sh[kq][0]), 0.f);
            float g1 = fmaxf(fmaf(f[1], sc[kq][1], sh[kq][1]), 0.f);
            float g2 = fmaxf(fmaf(f[2], sc[kq][2], sh[kq][2]), 0.f);
            float g3 = fmaxf(fmaf(f[3], sc[kq][3], sh[kq][3]), 0.f);
            float g4 = fmaxf(fmaf(f[4], sc[kq][4], sh[kq][4]), 0.f);
            float g5 = fmaxf(fmaf(f[5], sc[kq][5], sh[kq][5]), 0.f);
            float g6 = fmaxf(fmaf(f[6], sc[kq][6], sh[kq][6]), 0.f);
            float g7 = fmaxf(fmaf(f[7], sc[kq][7], sh[kq][7]), 0.f);
            uint4 a;
            a.x = pkbf(g0, g1); a.y = pkbf(g2, g3);
            a.z = pkbf(g4, g5); a.w = pkbf(g6, g7);
            Af[mt][kq] = asbf(a);
        }

    f32x4 acc[2][NT];
#pragma unroll
    for (int mt = 0; mt < 2; mt++)
#pragma unroll
        for (int nt = 0; nt < NT; nt++) acc[mt][nt] = (f32x4){0.f, 0.f, 0.f, 0.f};
#pragma unroll
    for (int mt = 0; mt < 2; mt++)
#pragma unroll
        for (int nt = 0; nt < NT; nt++) {
            acc[mt][nt] = __builtin_amdgcn_mfma_f32_16x16x32_bf16(Af[mt][0], Bf[nt][0], acc[mt][nt], 0, 0, 0);
            acc[mt][nt] = __builtin_amdgcn_mfma_f32_16x16x32_bf16(Af[mt][1], Bf[nt][1], acc[mt][nt], 0, 0, 0);
        }
    float s_[NT], q_[NT], xm[NT], xn[NT];
#pragma unroll
    for (int nt = 0; nt < NT; nt++) { s_[nt] = 0.f; q_[nt] = 0.f; xm[nt] = -3e38f; xn[nt] = 3e38f; }
#pragma unroll
    for (int nt = 0; nt < NT; nt++) {
        const float bs = bias[nt * 16 + l15];
#pragma unroll
        for (int mt = 0; mt < 2; mt++) {
#pragma unroll
            for (int r = 0; r < 4; r++) {
                float x = acc[mt][nt][r] + bs;
                s_[nt] += x; q_[nt] += x * x;
                xm[nt] = fmaxf(xm[nt], x); xn[nt] = fminf(xn[nt], x);
            }
        }
    }
    // reduce over the 4 quads (same channel l15, same s-group)
#pragma unroll
    for (int nt = 0; nt < NT; nt++) {
        s_[nt] += __shfl_xor(s_[nt], 16, 64); s_[nt] += __shfl_xor(s_[nt], 32, 64);
        q_[nt] += __shfl_xor(q_[nt], 16, 64); q_[nt] += __shfl_xor(q_[nt], 32, 64);
        xm[nt] = fmaxf(xm[nt], __shfl_xor(xm[nt], 16, 64));
        xm[nt] = fmaxf(xm[nt], __shfl_xor(xm[nt], 32, 64));
        xn[nt] = fminf(xn[nt], __shfl_xor(xn[nt], 16, 64));
        xn[nt] = fminf(xn[nt], __shfl_xor(xn[nt], 32, 64));
    }
    if (quad == 0) {
#pragma unroll
        for (int nt = 0; nt < NT; nt++) {
            const int ch = nt * 16 + l15;
            xmax[(size_t)g * 128 + ch] = xm[nt];
            xmin[(size_t)g * 128 + ch] = xn[nt];
        }
    }
    __shared__ float reds[4][NT][16], redq[4][NT][16];
    if (lane < 16) {
#pragma unroll
        for (int nt = 0; nt < NT; nt++) { reds[wid][nt][lane] = s_[nt]; redq[wid][nt][lane] = q_[nt]; }
    }
    __syncthreads();
    if (threadIdx.x < 16) {
#pragma unroll
        for (int nt = 0; nt < NT; nt++) {
            float ss = 0.f, qq = 0.f;
#pragma unroll
            for (int w = 0; w < 4; w++) { ss += reds[w][nt][threadIdx.x]; qq += redq[w][nt][threadIdx.x]; }
            const int ch = nt * 16 + threadIdx.x;
            part_s[(size_t)ch * NBLK + blockIdx.x] = ss;
            part_q[(size_t)ch * NBLK + blockIdx.x] = qq;
        }
    }
}

// ---------------------------------------------------------------- reduce partials -> BN scale/shift
__global__ __launch_bounds__(256) void reduce_finalize(const float* __restrict__ part_s,
                                                       const float* __restrict__ part_q,
                                                       const float* __restrict__ g,
                                                       const float* __restrict__ be,
                                                       float* __restrict__ scale,
                                                       float* __restrict__ shift) {
    const int ch = blockIdx.x;
    const float* p1 = part_s + (size_t)ch * NBLK;
    const float* p2 = part_q + (size_t)ch * NBLK;
    float s = 0.f, q = 0.f;
    for (int i = threadIdx.x; i < NBLK; i += 256) { s += p1[i]; q += p2[i]; }
#pragma unroll
    for (int m = 1; m < 64; m <<= 1) { s += __shfl_xor(s, m, 64); q += __shfl_xor(q, m, 64); }
    __shared__ float ls[4], lq[4];
    const int lane = threadIdx.x & 63, wid = threadIdx.x >> 6;
    if (lane == 0) { ls[wid] = s; lq[wid] = q; }
    __syncthreads();
    if (threadIdx.x == 0) {
        float ssum = ls[0] + ls[1] + ls[2] + ls[3];
        float qsum = lq[0] + lq[1] + lq[2] + lq[3];
        float mean = ssum * (1.f / (float)NPOS);
        float var = qsum * (1.f / (float)NPOS) - mean * mean;
        float inv = 1.f / sqrtf(var + EPSV);
        float sc = g[ch] * inv;
        scale[ch] = sc;
        shift[ch] = be[ch] - mean * sc;
    }
}

// ---------------------------------------------------------------- final: out[b,ch,s] = relu(sc*(sc>0?xmax:xmin)+sh)
// 128 blocks: b (16) x 8 tiles of 128 s. LDS transpose for coalesced writes.
__global__ __launch_bounds__(256) void final2_kernel(const float* __restrict__ xmax,
                                                     const float* __restrict__ xmin,
                                                     const float* __restrict__ scale,
                                                     const float* __restrict__ shift,
                                                     float* __restrict__ out) {
    __shared__ float buf[128][129];   // ~66 KB, pad to kill bank conflicts
    const int b = blockIdx.x >> 3;
    const int s0 = (blockIdx.x & 7) * 128;
    const int tid = threadIdx.x;
    for (int i = tid; i < 128 * 128; i += 256) {
        const int si = i >> 7, ch = i & 127;
        const size_t g = (size_t)(b * NPOINT + s0 + si);
        const float sc = scale[ch], sh = shift[ch];
        const float xM = xmax[g * 128 + ch];
        const float xN = xmin[g * 128 + ch];
        const float X = sc > 0.f ? xM : xN;
        buf[si][ch] = fmaxf(fmaf(X, sc, sh), 0.f);
    }
    __syncthreads();
    for (int i = tid; i < 128 * 128; i += 256) {
        const int ch = i >> 7, si = i & 127;
        out[((size_t)(b * 128 + ch)) * NPOINT + s0 + si] = buf[si][ch];
    }
}

// ---------------------------------------------------------------- launch
extern "C" void kernel_launch(void* const* d_in, const int* in_sizes, int n_in,
                              void* d_out, int out_size, void* d_ws, size_t ws_size,
                              hipStream_t stream) {
    const float* xyz = (const float*)d_in[0];
    const float* points = (const float*)d_in[1];
    const float* w0 = (const float*)d_in[2];
    const float* b0 = (const float*)d_in[3];
    const float* g0 = (const float*)d_in[4];
    const float* be0 = (const float*)d_in[5];
    const float* w1 = (const float*)d_in[6];
    const float* b1 = (const float*)d_in[7];
    const float* g1 = (const float*)d_in[8];
    const float* be1 = (const float*)d_in[9];
    const float* w2 = (const float*)d_in[10];
    const float* b2 = (const float*)d_in[11];
    const float* g2 = (const float*)d_in[12];
    const float* be2 = (const float*)d_in[13];

    float* out = (float*)d_out;
    float* new_xyz = out;                      // B*NPOINT*3 = 49152
    float* final_out = out + BATCH * NPOINT * 3;

    // workspace layout (~150 MiB): gidx | Y2 | Y1 | params | parts | weights | xmax | xmin
    char* ws = (char*)d_ws;
    const size_t MB = 1024u * 1024u;
    const size_t o_gidx = 0;                                  // 2 MiB
    const size_t o_y2 = 2 * MB;                               // 64 MiB
    const size_t o_y1 = o_y2 + (size_t)NPOS * 64 * 2;         // 64 MiB
    const size_t o_params = o_y1 + (size_t)NPOS * 64 * 2;     // 512 floats
    const size_t o_parts = o_params + 4096;                   // 4 MiB
    const size_t o_w = o_parts + 4 * MB;                      // ~32 KiB
    const size_t o_xm = o_w + 64 * 1024;                      // 8 MiB
    const size_t o_xn = o_xm + (size_t)NGRP * 128 * 4;        // 8 MiB

    int* gidx = (int*)(ws + o_gidx);
    ushort_t* Y1 = (ushort_t*)(ws + o_y1);
    ushort_t* Y2 = (ushort_t*)(ws + o_y2);
    float* pr = (float*)(ws + o_params);
    float* scale1 = pr + 0, *shift1 = pr + 64;
    float* scale2 = pr + 128, *shift2 = pr + 192;
    float* scale3 = pr + 256, *shift3 = pr + 384;
    float* part_s = (float*)(ws + o_parts);
    float* part_q = part_s + (size_t)128 * NBLK;
    ushort_t* Wp0 = (ushort_t*)(ws + o_w);
    ushort_t* Wx0 = Wp0 + 64 * 32;
    ushort_t* Wp1 = Wx0 + 64 * 4;
    ushort_t* Wp2 = Wp1 + 64 * 64;
    float* xmax = (float*)(ws + o_xm);
    float* xmin = (float*)(ws + o_xn);

    prep_w<<<8, 256, 0, stream>>>(w0, w1, w2, Wp0, Wx0, Wp1, Wp2);
    fps_kernel<<<BATCH, 256, 0, stream>>>(xyz, new_xyz);
    ballq_kernel<<<(BATCH * NPOINT) / 4, 256, 0, stream>>>(xyz, new_xyz, gidx);
    conv1_mfma<<<NBLK, 256, 0, stream>>>(xyz, points, new_xyz, gidx, Wp0, Wx0, b0, Y1, part_s, part_q);
    reduce_finalize<<<64, 256, 0, stream>>>(part_s, part_q, g0, be0, scale1, shift1);
    conv2_mfma<<<NBLK, 256, 0, stream>>>(Y1, scale1, shift1, Wp1, b1, Y2, part_s, part_q);
    reduce_finalize<<<64, 256, 0, stream>>>(part_s, part_q, g1, be1, scale2, shift2);
    conv3_mfma<<<NBLK, 256, 0, stream>>>(Y2, scale2, shift2, Wp2, b2, xmax, xmin, part_s, part_q);
    reduce_finalize<<<128, 256, 0, stream>>>(part_s, part_q, g2, be2, scale3, shift3);
    final2_kernel<<<128, 256, 0, stream>>>(xmax, xmin, scale3, shift3, final_out);
}